// Round 2
// baseline (5262.041 us; speedup 1.0000x reference)
//
#include <hip/hip_runtime.h>

typedef float f4 __attribute__((ext_vector_type(4)));
typedef float f2 __attribute__((ext_vector_type(2)));

// ---------------- workspace layout (float offsets) ----------------
enum : size_t {
  OFF_A  = 0,           // 8,388,608 floats  ping buffer
  OFF_B  = 8388608,     // 4,194,304 floats  pong buffer
  OFF_P  = 12582912,    // 4,194,304 floats  conv c-split partial sums
  OFF_PK = 16777216,    //   294,912 floats  pac-kernel partial sums
  OFF_WT = 17072128,    // 21,971,520 floats transposed weights
  WS_FULL_FLOATS = 39043648,
};

// ---------------- d_out layout (float offsets), return order ----------------
enum : size_t {
  O_H1 = 0,          // [2,64,256,256]
  O_H2 = 8388608,    // [2,128,128,128]
  O_H3 = 12582912,   // [2,256,64,64]
  O_H4 = 14680064,   // [2,512,32,32]
  O_H5 = 15728640,   // [2,1024,16,16]
  O_K2 = 16252928,   // [2,9,128,128]
  O_K3 = 16547840,   // [2,9,64,64]
  O_K4 = 16621568,   // [2,9,32,32]
  O_K5 = 16640000,   // [2,9,16,16]
};

// ---------------------------------------------------------------------------
// Tiled 3x3 conv (pad=1). Block: 256 thr = 8 ocg x 32 pxg.
// Tile: 64 oc x (TH rows x TW cols), TH = 256/TW. Per thread: 8 oc x 8 px.
// x staged in LDS (vector b128/b64 reads, padded stride). Weights read
// directly from global (transposed [ci][9][oc] if wmode, else scattered).
// SP=1: atomic partial sums (bias/relu in epilogue kernel).
// ---------------------------------------------------------------------------
template<int S, int HK, int SP, int KC, int TW>
__global__ __launch_bounds__(256, 2) void conv3x3_k(
    const float* __restrict__ src, const float* __restrict__ wsrc, int wmode,
    const float* __restrict__ bias, const float* __restrict__ kern,
    float* __restrict__ dst, int Cin, int Cout, int H, int CS)
{
  constexpr int TH  = 256 / TW;
  constexpr int RH  = TH * S + 2;
  constexpr int RW  = TW * S + 2;
  constexpr int RW4 = (RW + 3) & ~3;
  constexpr int RWs = (RW4 % 8 == 0) ? RW4 + 4 : RW4;   // 16B-aligned rows, bank-staggered
  constexpr int CPT = TW / 8;                            // col-groups per row

  __shared__ __align__(16) float xs[KC][RH][RWs];

  const int W = H, HW = H * W;
  const int OH = H / S, OW = W / S;
  const int tid  = threadIdx.x;
  const int ocg  = tid >> 5;
  const int pxg  = tid & 31;
  const int prow = pxg / CPT;
  const int pcol = (pxg % CPT) * 8;
  const int tiles_w = OW / TW;
  const int th0 = (blockIdx.x / tiles_w) * TH;
  const int tw0 = (blockIdx.x % tiles_w) * TW;
  const int ocb = blockIdx.y * 64;
  const int bz  = blockIdx.z;
  const int b   = bz / CS, cs = bz - b * CS;
  const int CinS   = Cin / CS;
  const int c_base = cs * CinS;
  const int oh  = th0 + prow;
  const int ow0 = tw0 + pcol;
  const int oc0 = ocb + (ocg << 3);

  float acc[8][8];
#pragma unroll
  for (int o = 0; o < 8; ++o)
#pragma unroll
    for (int p = 0; p < 8; ++p) acc[o][p] = 0.f;

  // PAC factors (kern spatial dims = input H,W; stride-S view)
  float kf[9][8];
  if (HK) {
#pragma unroll
    for (int t = 0; t < 9; ++t) {
      const float* kp = kern + ((size_t)(b * 9 + t) * H + (size_t)oh * S) * W
                             + (size_t)ow0 * S;
      if constexpr (S == 1) {
        f4 a = *(const f4*)kp; f4 c = *(const f4*)(kp + 4);
#pragma unroll
        for (int p = 0; p < 4; ++p) { kf[t][p] = a[p]; kf[t][4 + p] = c[p]; }
      } else {
#pragma unroll
        for (int p = 0; p < 8; ++p) kf[t][p] = kp[2 * p];
      }
    }
  }

  const float* xb = src + (size_t)b * Cin * HW;

  for (int c0 = c_base; c0 < c_base + CinS; c0 += KC) {
    // ---- stage input tile ----
    constexpr int TOT = KC * RH * RW;
    for (int idx = tid; idx < TOT; idx += 256) {
      int kc  = idx / (RH * RW);
      int rem = idx - kc * (RH * RW);
      int r   = rem / RW;
      int col = rem - r * RW;
      int ih = th0 * S + r - 1;
      int iw = tw0 * S + col - 1;
      float v = 0.f;
      if (ih >= 0 && ih < H && iw >= 0 && iw < W)
        v = xb[(size_t)(c0 + kc) * HW + (size_t)ih * W + iw];
      xs[kc][r][col] = v;
    }
    __syncthreads();

#pragma unroll 1
    for (int kc = 0; kc < KC; ++kc) {
      const int cch = c0 + kc;
#pragma unroll
      for (int di = 0; di < 3; ++di) {
        // weights for taps t = 3*di + {0,1,2}: 8 oc each
        f4 wv[3][2];
        if (wmode) {
          const float* wp = wsrc + ((size_t)cch * 9 + di * 3) * Cout + oc0;
#pragma unroll
          for (int dj = 0; dj < 3; ++dj) {
            wv[dj][0] = *(const f4*)(wp + dj * Cout);
            wv[dj][1] = *(const f4*)(wp + dj * Cout + 4);
          }
        } else {
#pragma unroll
          for (int dj = 0; dj < 3; ++dj)
#pragma unroll
            for (int o = 0; o < 8; ++o)
              wv[dj][o >> 2][o & 3] =
                  wsrc[((size_t)(oc0 + o) * Cin + cch) * 9 + di * 3 + dj];
        }

        const float* xrow = &xs[kc][prow * S + di][pcol * S];
        f4 xa, xbv, xc, xd; f2 xe2; float xe;
        xa  = *(const f4*)xrow;
        xbv = *(const f4*)(xrow + 4);
        if constexpr (S == 1) {
          xe2 = *(const f2*)(xrow + 8);
        } else {
          xc = *(const f4*)(xrow + 8);
          xd = *(const f4*)(xrow + 12);
          xe = xrow[16];
        }
        auto xget = [&](int q) -> float {
          if constexpr (S == 1)
            return (q < 4) ? xa[q] : (q < 8) ? xbv[q - 4] : xe2[q - 8];
          else
            return (q < 4) ? xa[q] : (q < 8) ? xbv[q - 4]
                 : (q < 12) ? xc[q - 8] : (q < 16) ? xd[q - 12] : xe;
        };

#pragma unroll
        for (int dj = 0; dj < 3; ++dj) {
          float xq[8];
#pragma unroll
          for (int p = 0; p < 8; ++p) {
            float xvv = xget(S * p + dj);
            xq[p] = HK ? xvv * kf[di * 3 + dj][p] : xvv;
          }
#pragma unroll
          for (int o = 0; o < 8; ++o) {
            const float w = wv[dj][o >> 2][o & 3];
#pragma unroll
            for (int p = 0; p < 8; ++p)
              acc[o][p] = fmaf(w, xq[p], acc[o][p]);
          }
        }
      }
    }
    __syncthreads();
  }

  // ---- writeback ----
#pragma unroll
  for (int o = 0; o < 8; ++o) {
    const int oc = oc0 + o;
    float* orow = dst + ((size_t)b * Cout + oc) * OH * OW + (size_t)oh * OW + ow0;
    if constexpr (SP) {
#pragma unroll
      for (int p = 0; p < 8; ++p) atomicAdd(&orow[p], acc[o][p]);
    } else {
      const float bo = bias[oc];
      f4 r0, r1;
#pragma unroll
      for (int p = 0; p < 4; ++p) {
        r0[p] = fmaxf(acc[o][p] + bo, 0.f);
        r1[p] = fmaxf(acc[o][4 + p] + bo, 0.f);
      }
      *(f4*)orow = r0; *(f4*)(orow + 4) = r1;
    }
  }
}

// ---------------------------------------------------------------------------
// PAC kernel stage 1: s[b][t][h][w] += sum_c (x[c,h+di-1,w+dj-1]-x[c,h,w])^2
// (always atomic into zeroed buffer; channel split via blockIdx.y)
// ---------------------------------------------------------------------------
template<int KCC>
__global__ __launch_bounds__(256) void pac_s1(
    const float* __restrict__ g, float* __restrict__ s,
    int C, int H, int W, int CS)
{
  __shared__ float xs[KCC][18][19];
  const int tid = threadIdx.x;
  const int pr = tid >> 4, pc = tid & 15;
  const int tiles_w = W / 16;
  const int tile = blockIdx.x;
  const int th0 = (tile / tiles_w) * 16, tw0 = (tile % tiles_w) * 16;
  const int bz = blockIdx.y;
  const int b = bz / CS, cs = bz - b * CS;
  const int CinS = C / CS, c0b = cs * CinS;

  float acc[9];
#pragma unroll
  for (int t = 0; t < 9; ++t) acc[t] = 0.f;

  const float* gb = g + (size_t)b * C * H * W;
  for (int c0 = c0b; c0 < c0b + CinS; c0 += KCC) {
    for (int idx = tid; idx < KCC * 18 * 18; idx += 256) {
      int kc = idx / 324;
      int rem = idx - kc * 324;
      int r = rem / 18, col = rem - r * 18;
      int ih = th0 + r - 1, iw = tw0 + col - 1;
      float v = 0.f;
      if (ih >= 0 && ih < H && iw >= 0 && iw < W)
        v = gb[(size_t)(c0 + kc) * H * W + (size_t)ih * W + iw];
      xs[kc][r][col] = v;
    }
    __syncthreads();
#pragma unroll
    for (int kc = 0; kc < KCC; ++kc) {
      float xcv = xs[kc][pr + 1][pc + 1];
#pragma unroll
      for (int di = 0; di < 3; ++di)
#pragma unroll
        for (int dj = 0; dj < 3; ++dj) {
          float d = xs[kc][pr + di][pc + dj] - xcv;
          acc[di * 3 + dj] = fmaf(d, d, acc[di * 3 + dj]);
        }
    }
    __syncthreads();
  }

  size_t base = (size_t)b * 9 * H * W + (size_t)(th0 + pr) * W + tw0 + pc;
#pragma unroll
  for (int t = 0; t < 9; ++t) {
    size_t a = base + (size_t)t * H * W;
    if (CS > 1) atomicAdd(&s[a], acc[t]);
    else        s[a] = acc[t];
  }
}

// stage 2: k = exp(-0.5 * coeff^2 * s)
__global__ __launch_bounds__(256) void pac_s2(
    const float* __restrict__ s, float* __restrict__ k, float c2, int n)
{
  int i = blockIdx.x * 256 + threadIdx.x;
  if (i < n) k[i] = expf(-0.5f * c2 * s[i]);
}

// epilogue for c-split convs: out = relu(partial + bias[c])
__global__ __launch_bounds__(256) void bias_relu_k(
    const float* __restrict__ p, const float* __restrict__ bias,
    float* __restrict__ out, int C, int HW, int n)
{
  int i = blockIdx.x * 256 + threadIdx.x;
  if (i < n) {
    int c = (i / HW) % C;
    out[i] = fmaxf(p[i] + bias[c], 0.f);
  }
}

// weight transpose: [Cout][Cin][3][3] -> [Cin][9][Cout], all 14 layers
struct TPack {
  const float* src[14];
  float* dst[14];
  int ci[14];
  int co[14];
};

__global__ __launch_bounds__(256) void transpose_w(TPack p)
{
  for (int l = 0; l < 14; ++l) {
    const int ci = p.ci[l], co = p.co[l];
    const int n = ci * co * 9;
    const float* s = p.src[l];
    float* d = p.dst[l];
    for (int idx = blockIdx.x * 256 + threadIdx.x; idx < n;
         idx += gridDim.x * 256) {
      int c = idx / (9 * co);
      int rem = idx - c * 9 * co;
      int t = rem / co;
      int oc = rem - t * co;
      d[idx] = s[((size_t)oc * ci + c) * 9 + t];
    }
  }
}

// ---------------------------------------------------------------------------
// host-side dispatch
// ---------------------------------------------------------------------------
#define LAUNCH_CONV(KER, S, TW, src, w, bias, kern, dst, Cin, Cout, H, CS)     \
  do {                                                                         \
    const int OH_ = (H) / (S);                                                 \
    const int TH_ = 256 / (TW);                                                \
    dim3 g_((OH_ / TH_) * (OH_ / (TW)), (Cout) / 64, 2 * (CS));                \
    KER<<<g_, 256, 0, stream>>>(src, w, wmode, bias, kern, dst, Cin, Cout, H,  \
                                CS);                                           \
  } while (0)

extern "C" void kernel_launch(void* const* d_in, const int* in_sizes, int n_in,
                              void* d_out, int out_size, void* d_ws, size_t ws_size,
                              hipStream_t stream)
{
  (void)in_sizes; (void)n_in; (void)out_size;
  const float* x = (const float*)d_in[0];
  const float* Wp[14];
  const float* Bp[14];
  for (int l = 0; l < 14; ++l) {
    Wp[l] = (const float*)d_in[1 + 2 * l];
    Bp[l] = (const float*)d_in[2 + 2 * l];
  }
  float* out = (float*)d_out;
  float* ws  = (float*)d_ws;

  float* A  = ws + OFF_A;
  float* Bf = ws + OFF_B;
  float* P  = ws + OFF_P;
  float* Pk = ws + OFF_PK;
  float* WT = ws + OFF_WT;

  const int ci[14] = {1,64,64, 64,128,128, 128,256,256, 256,512,512, 512,1024};
  const int co[14] = {64,64,64, 128,128,128, 256,256,256, 512,512,512, 1024,1024};

  const int wmode = (ws_size >= (size_t)WS_FULL_FLOATS * 4) ? 1 : 0;

  const float* wl[14];
  if (wmode) {
    size_t off = 0;
    TPack tp;
    for (int l = 0; l < 14; ++l) {
      tp.src[l] = Wp[l];
      tp.dst[l] = WT + off;
      tp.ci[l] = ci[l];
      tp.co[l] = co[l];
      wl[l] = WT + off;
      off += (size_t)ci[l] * co[l] * 9;
    }
    transpose_w<<<2048, 256, 0, stream>>>(tp);
  } else {
    for (int l = 0; l < 14; ++l) wl[l] = Wp[l];
  }

  float* h1 = out + O_H1;
  float* h2 = out + O_H2;
  float* h3 = out + O_H3;
  float* h4 = out + O_H4;
  float* h5 = out + O_H5;
  float* k2 = out + O_K2;
  float* k3 = out + O_K3;
  float* k4 = out + O_K4;
  float* k5 = out + O_K5;

  // helpers for split convs
  auto memz = [&](float* p, int n) { hipMemsetAsync(p, 0, (size_t)n * 4, stream); };
  auto epi  = [&](const float* p, const float* bias, float* dst, int C, int HWo) {
    int n = 2 * C * HWo;
    bias_relu_k<<<(n + 255) / 256, 256, 0, stream>>>(p, bias, dst, C, HWo, n);
  };

  // ---- stage 1 ----
  LAUNCH_CONV((conv3x3_k<1,0,0,1,32>), 1, 32, x,  wl[0], Bp[0], nullptr, A,  1,  64, 256, 1);
  LAUNCH_CONV((conv3x3_k<1,0,0,8,32>), 1, 32, A,  wl[1], Bp[1], nullptr, h1, 64, 64, 256, 1);
  // 1_3 stride-2, split CS=4 -> P -> Bf[2,64,128,128]
  memz(P, 2 * 64 * 128 * 128);
  LAUNCH_CONV((conv3x3_k<2,0,1,4,32>), 2, 32, h1, wl[2], nullptr, nullptr, P, 64, 64, 256, 4);
  epi(P, Bp[2], Bf, 64, 128 * 128);

  // ---- k2 ----
  {
    int n = 2 * 9 * 128 * 128;
    memz(Pk, n);
    dim3 g(64, 2 * 4);
    pac_s1<4><<<g, 256, 0, stream>>>(Bf, Pk, 64, 128, 128, 4);
    pac_s2<<<(n + 255) / 256, 256, 0, stream>>>(Pk, k2, 1e-8f, n);
  }

  // 2_1: Bf -> P(CS=2) -> A[2,128,128,128]
  memz(P, 2 * 128 * 128 * 128);
  LAUNCH_CONV((conv3x3_k<1,1,1,8,32>), 1, 32, Bf, wl[3], nullptr, k2, P, 64, 128, 128, 2);
  epi(P, Bp[3], A, 128, 128 * 128);
  // 2_2: A -> P(CS=2) -> h2
  memz(P, 2 * 128 * 128 * 128);
  LAUNCH_CONV((conv3x3_k<1,1,1,8,32>), 1, 32, A,  wl[4], nullptr, k2, P, 128, 128, 128, 2);
  epi(P, Bp[4], h2, 128, 128 * 128);
  // 2_3: h2 -> P(CS=8, stride 2) -> Bf[2,128,64,64]
  memz(P, 2 * 128 * 64 * 64);
  LAUNCH_CONV((conv3x3_k<2,1,1,4,32>), 2, 32, h2, wl[5], nullptr, k2, P, 128, 128, 128, 8);
  epi(P, Bp[5], Bf, 128, 64 * 64);

  // ---- k3 ----
  {
    int n = 2 * 9 * 64 * 64;
    memz(Pk, n);
    dim3 g(16, 2 * 8);
    pac_s1<4><<<g, 256, 0, stream>>>(Bf, Pk, 128, 64, 64, 8);
    pac_s2<<<(n + 255) / 256, 256, 0, stream>>>(Pk, k3, 1e-8f, n);
  }

  // 3_1: Bf -> P(CS=4) -> A[2,256,64,64]
  memz(P, 2 * 256 * 64 * 64);
  LAUNCH_CONV((conv3x3_k<1,1,1,8,32>), 1, 32, Bf, wl[6], nullptr, k3, P, 128, 256, 64, 4);
  epi(P, Bp[6], A, 256, 64 * 64);
  // 3_2: A -> P(CS=4) -> h3
  memz(P, 2 * 256 * 64 * 64);
  LAUNCH_CONV((conv3x3_k<1,1,1,8,32>), 1, 32, A,  wl[7], nullptr, k3, P, 256, 256, 64, 4);
  epi(P, Bp[7], h3, 256, 64 * 64);
  // 3_3: h3 -> P(CS=16, stride 2) -> Bf[2,256,32,32]
  memz(P, 2 * 256 * 32 * 32);
  LAUNCH_CONV((conv3x3_k<2,1,1,4,32>), 2, 32, h3, wl[8], nullptr, k3, P, 256, 256, 64, 16);
  epi(P, Bp[8], Bf, 256, 32 * 32);

  // ---- k4 (coeff 2.0 -> c2 = 4) ----
  {
    int n = 2 * 9 * 32 * 32;
    memz(Pk, n);
    dim3 g(4, 2 * 16);
    pac_s1<4><<<g, 256, 0, stream>>>(Bf, Pk, 256, 32, 32, 16);
    pac_s2<<<(n + 255) / 256, 256, 0, stream>>>(Pk, k4, 4.0f, n);
  }

  // 4_1: Bf -> P(CS=8) -> A[2,512,32,32]
  memz(P, 2 * 512 * 32 * 32);
  LAUNCH_CONV((conv3x3_k<1,1,1,8,32>), 1, 32, Bf, wl[9], nullptr, k4, P, 256, 512, 32, 8);
  epi(P, Bp[9], A, 512, 32 * 32);
  // 4_2: A -> P(CS=8) -> h4
  memz(P, 2 * 512 * 32 * 32);
  LAUNCH_CONV((conv3x3_k<1,1,1,8,32>), 1, 32, A,  wl[10], nullptr, k4, P, 512, 512, 32, 8);
  epi(P, Bp[10], h4, 512, 32 * 32);
  // 4_3: h4 -> P(CS=32, stride 2, 16x16 tile) -> Bf[2,512,16,16]
  memz(P, 2 * 512 * 16 * 16);
  LAUNCH_CONV((conv3x3_k<2,1,1,4,16>), 2, 16, h4, wl[11], nullptr, k4, P, 512, 512, 32, 32);
  epi(P, Bp[11], Bf, 512, 16 * 16);

  // ---- k5 ----
  {
    int n = 2 * 9 * 16 * 16;
    memz(Pk, n);
    dim3 g(1, 2 * 64);
    pac_s1<4><<<g, 256, 0, stream>>>(Bf, Pk, 512, 16, 16, 64);
    pac_s2<<<(n + 255) / 256, 256, 0, stream>>>(Pk, k5, 1e-8f, n);
  }

  // 5_1: Bf -> P(CS=16, 16x16 tile) -> A[2,1024,16,16]
  memz(P, 2 * 1024 * 16 * 16);
  LAUNCH_CONV((conv3x3_k<1,1,1,8,16>), 1, 16, Bf, wl[12], nullptr, k5, P, 512, 1024, 16, 16);
  epi(P, Bp[12], A, 1024, 16 * 16);
  // 5_2: A -> P(CS=16) -> h5
  memz(P, 2 * 1024 * 16 * 16);
  LAUNCH_CONV((conv3x3_k<1,1,1,8,16>), 1, 16, A,  wl[13], nullptr, k5, P, 1024, 1024, 16, 16);
  epi(P, Bp[13], h5, 1024, 16 * 16);
}

// Round 4
// 2705.450 us; speedup vs baseline: 1.9450x; 1.9450x over previous
//
#include <hip/hip_runtime.h>

typedef float f4 __attribute__((ext_vector_type(4)));
typedef float f2 __attribute__((ext_vector_type(2)));

// ---------------- workspace layout (float offsets) ----------------
enum : size_t {
  OFF_A  = 0,           // 8,388,608 floats  ping buffer
  OFF_B  = 8388608,     // 4,194,304 floats  pong buffer
  OFF_P  = 12582912,    // 4,194,304 floats  partial sums (conv + pac)
  OFF_PK = 16777216,    //   294,912 floats  (unused)
  OFF_WT = 17072128,    // 21,971,520 floats transposed weights
  WS_FULL_FLOATS = 39043648,
};

// ---------------- d_out layout (float offsets), return order ----------------
enum : size_t {
  O_H1 = 0,          // [2,64,256,256]
  O_H2 = 8388608,    // [2,128,128,128]
  O_H3 = 12582912,   // [2,256,64,64]
  O_H4 = 14680064,   // [2,512,32,32]
  O_H5 = 15728640,   // [2,1024,16,16]
  O_K2 = 16252928,   // [2,9,128,128]
  O_K3 = 16547840,   // [2,9,64,64]
  O_K4 = 16621568,   // [2,9,32,32]
  O_K5 = 16640000,   // [2,9,16,16]
};

// ---------------------------------------------------------------------------
// Tiled 3x3 conv (pad=1). Block: 256 thr = 8 ocg x 32 pxg.
// Tile: OCB oc x (TH x TW) px, TH = 256/TW. Per thread: OPT=OCB/8 oc x 8 px.
// x and weights double-buffered: global->regs issued one chunk ahead,
// regs->LDS after barrier. Weights read from LDS as f4 (half-wave broadcast).
// PS=1: plain partial store to dst + cs*outsize (no bias/relu, no atomics).
// ---------------------------------------------------------------------------
template<int S, int HK, int PS, int KC, int TW, int OCB>
__global__ __launch_bounds__(256, 2) void conv3x3_k(
    const float* __restrict__ src, const float* __restrict__ wsrc, int wmode,
    const float* __restrict__ bias, const float* __restrict__ kern,
    float* __restrict__ dst, int Cin, int Cout, int H, int CS)
{
  constexpr int TH  = 256 / TW;
  constexpr int RH  = TH * S + 2;
  constexpr int RW  = TW * S + 2;
  constexpr int RW4 = (RW + 3) & ~3;
  constexpr int RWs = (RW4 % 8 == 0) ? RW4 + 4 : RW4;  // 16B rows, bank-staggered
  constexpr int CPT = TW / 8;
  constexpr int OPT = OCB / 8;
  constexpr int TOTX = KC * RH * RW;
  constexpr int NLX  = (TOTX + 255) / 256;
  constexpr int TOTW = KC * 9 * OCB;
  constexpr int NLW  = (TOTW + 255) / 256;

  __shared__ __align__(16) float xs[KC][RH][RWs];
  __shared__ __align__(16) float wsm[KC][9][OCB];

  const int W = H, HW = H * W;
  const int OH = H / S, OW = W / S;
  const int tid  = threadIdx.x;
  const int ocg  = tid >> 5;
  const int pxg  = tid & 31;
  const int prow = pxg / CPT;
  const int pcol = (pxg % CPT) * 8;
  const int tiles_w = OW / TW;
  const int th0 = (blockIdx.x / tiles_w) * TH;
  const int tw0 = (blockIdx.x % tiles_w) * TW;
  const int ocb = blockIdx.y * OCB;
  const int bz  = blockIdx.z;
  const int b   = bz / CS, cs = bz - b * CS;
  const int CinS   = Cin / CS;
  const int c_base = cs * CinS;
  const int c_end  = c_base + CinS;
  const int oh  = th0 + prow;
  const int ow0 = tw0 + pcol;
  const int oc0 = ocb + ocg * OPT;

  float acc[OPT][8];
#pragma unroll
  for (int o = 0; o < OPT; ++o)
#pragma unroll
    for (int p = 0; p < 8; ++p) acc[o][p] = 0.f;

  float kf[HK ? 9 : 1][8];
  if (HK) {
#pragma unroll
    for (int t = 0; t < 9; ++t) {
      const float* kp = kern + ((size_t)(b * 9 + t) * H + (size_t)oh * S) * W
                             + (size_t)ow0 * S;
      if constexpr (S == 1) {
        f4 a = *(const f4*)kp; f4 c = *(const f4*)(kp + 4);
#pragma unroll
        for (int p = 0; p < 4; ++p) { kf[t][p] = a[p]; kf[t][4 + p] = c[p]; }
      } else {
#pragma unroll
        for (int p = 0; p < 8; ++p) kf[t][p] = kp[2 * p];
      }
    }
  }

  const float* xb = src + (size_t)b * Cin * HW;

  float xr[NLX], wr[NLW];

  auto loadX = [&](int c0) {
#pragma unroll
    for (int l = 0; l < NLX; ++l) {
      const int idx = tid + l * 256;
      float v = 0.f;
      if (idx < TOTX) {
        int kc  = idx / (RH * RW);
        int rem = idx - kc * (RH * RW);
        int r   = rem / RW;
        int col = rem - r * RW;
        int ih = th0 * S + r - 1;
        int iw = tw0 * S + col - 1;
        if (ih >= 0 && ih < H && iw >= 0 && iw < W)
          v = xb[(size_t)(c0 + kc) * HW + (size_t)ih * W + iw];
      }
      xr[l] = v;
    }
  };
  auto storeX = [&]() {
#pragma unroll
    for (int l = 0; l < NLX; ++l) {
      const int idx = tid + l * 256;
      if (idx < TOTX) {
        int kc  = idx / (RH * RW);
        int rem = idx - kc * (RH * RW);
        int r   = rem / RW;
        int col = rem - r * RW;
        xs[kc][r][col] = xr[l];
      }
    }
  };
  auto loadW = [&](int c0) {
#pragma unroll
    for (int l = 0; l < NLW; ++l) {
      const int idx = tid + l * 256;
      if (idx < TOTW) {
        int kc  = idx / (9 * OCB);
        int rem = idx - kc * (9 * OCB);
        int t   = rem / OCB;
        int o   = rem - t * OCB;
        wr[l] = wmode
          ? wsrc[((size_t)(c0 + kc) * 9 + t) * Cout + ocb + o]
          : wsrc[((size_t)(ocb + o) * Cin + (c0 + kc)) * 9 + t];
      }
    }
  };
  auto storeW = [&]() {
#pragma unroll
    for (int l = 0; l < NLW; ++l) {
      const int idx = tid + l * 256;
      if (idx < TOTW) {
        int kc  = idx / (9 * OCB);
        int rem = idx - kc * (9 * OCB);
        int t   = rem / OCB;
        int o   = rem - t * OCB;
        wsm[kc][t][o] = wr[l];
      }
    }
  };

  loadX(c_base);
  loadW(c_base);

  for (int c0 = c_base; c0 < c_end; c0 += KC) {
    storeX();
    storeW();
    __syncthreads();
    if (c0 + KC < c_end) { loadX(c0 + KC); loadW(c0 + KC); }

#pragma unroll 1
    for (int kc = 0; kc < KC; ++kc) {
#pragma unroll
      for (int di = 0; di < 3; ++di) {
        // x row for this (kc,di)
        const float* xrow = &xs[kc][prow * S + di][pcol * S];
        f4 xa, xbv, xc, xd; f2 xe2; float xe;
        xa  = *(const f4*)xrow;
        xbv = *(const f4*)(xrow + 4);
        if constexpr (S == 1) {
          xe2 = *(const f2*)(xrow + 8);
        } else {
          xc = *(const f4*)(xrow + 8);
          xd = *(const f4*)(xrow + 12);
          xe = xrow[16];
        }
        auto xget = [&](int q) -> float {
          if constexpr (S == 1)
            return (q < 4) ? xa[q] : (q < 8) ? xbv[q - 4] : xe2[q - 8];
          else
            return (q < 4) ? xa[q] : (q < 8) ? xbv[q - 4]
                 : (q < 12) ? xc[q - 8] : (q < 16) ? xd[q - 12] : xe;
        };

#pragma unroll
        for (int dj = 0; dj < 3; ++dj) {
          const int t = di * 3 + dj;
          f4 wv[OPT / 4 > 0 ? OPT / 4 : 1];
#pragma unroll
          for (int u = 0; u < OPT / 4; ++u)
            wv[u] = *(const f4*)&wsm[kc][t][ocg * OPT + 4 * u];

          float xq[8];
#pragma unroll
          for (int p = 0; p < 8; ++p) {
            float xvv = xget(S * p + dj);
            xq[p] = HK ? xvv * kf[t][p] : xvv;
          }
#pragma unroll
          for (int o = 0; o < OPT; ++o) {
            const float w = wv[o >> 2][o & 3];
#pragma unroll
            for (int p = 0; p < 8; ++p)
              acc[o][p] = fmaf(w, xq[p], acc[o][p]);
          }
        }
      }
    }
    __syncthreads();
  }

  // ---- writeback ----
  const size_t osz = (size_t)2 * Cout * OH * OW;
#pragma unroll
  for (int o = 0; o < OPT; ++o) {
    const int oc = oc0 + o;
    float* orow = dst + (PS ? (size_t)cs * osz : 0)
                + ((size_t)b * Cout + oc) * OH * OW + (size_t)oh * OW + ow0;
    f4 r0, r1;
    if constexpr (PS) {
#pragma unroll
      for (int p = 0; p < 4; ++p) { r0[p] = acc[o][p]; r1[p] = acc[o][4 + p]; }
    } else {
      const float bo = bias[oc];
#pragma unroll
      for (int p = 0; p < 4; ++p) {
        r0[p] = fmaxf(acc[o][p] + bo, 0.f);
        r1[p] = fmaxf(acc[o][4 + p] + bo, 0.f);
      }
    }
    *(f4*)orow = r0; *(f4*)(orow + 4) = r1;
  }
}

// ---------------------------------------------------------------------------
// PAC stage 1 (partial): s[cs][b][t][h][w] = sum_{c in slice} (diff)^2
// ---------------------------------------------------------------------------
template<int KCC>
__global__ __launch_bounds__(256) void pac_s1(
    const float* __restrict__ g, float* __restrict__ s,
    int C, int H, int W, int CS)
{
  __shared__ float xs[KCC][18][19];
  const int tid = threadIdx.x;
  const int pr = tid >> 4, pc = tid & 15;
  const int tiles_w = W / 16;
  const int tile = blockIdx.x;
  const int th0 = (tile / tiles_w) * 16, tw0 = (tile % tiles_w) * 16;
  const int bz = blockIdx.y;
  const int b = bz / CS, cs = bz - b * CS;
  const int CinS = C / CS, c0b = cs * CinS;

  float acc[9];
#pragma unroll
  for (int t = 0; t < 9; ++t) acc[t] = 0.f;

  const float* gb = g + (size_t)b * C * H * W;
  for (int c0 = c0b; c0 < c0b + CinS; c0 += KCC) {
    for (int idx = tid; idx < KCC * 18 * 18; idx += 256) {
      int kc = idx / 324;
      int rem = idx - kc * 324;
      int r = rem / 18, col = rem - r * 18;
      int ih = th0 + r - 1, iw = tw0 + col - 1;
      float v = 0.f;
      if (ih >= 0 && ih < H && iw >= 0 && iw < W)
        v = gb[(size_t)(c0 + kc) * H * W + (size_t)ih * W + iw];
      xs[kc][r][col] = v;
    }
    __syncthreads();
#pragma unroll
    for (int kc = 0; kc < KCC; ++kc) {
      float xcv = xs[kc][pr + 1][pc + 1];
#pragma unroll
      for (int di = 0; di < 3; ++di)
#pragma unroll
        for (int dj = 0; dj < 3; ++dj) {
          float d = xs[kc][pr + di][pc + dj] - xcv;
          acc[di * 3 + dj] = fmaf(d, d, acc[di * 3 + dj]);
        }
    }
    __syncthreads();
  }

  const size_t HWs = (size_t)H * W;
  float* sp = s + ((size_t)(cs * 2 + b) * 9) * HWs
            + (size_t)(th0 + pr) * W + tw0 + pc;
#pragma unroll
  for (int t = 0; t < 9; ++t) sp[t * HWs] = acc[t];
}

// stage 2: k[i] = exp(-0.5*c2 * sum_cs P[cs*n+i])
__global__ __launch_bounds__(256) void pac_sum_exp(
    const float* __restrict__ P, float* __restrict__ k, float c2, int n, int CS)
{
  int i = blockIdx.x * 256 + threadIdx.x;
  if (i < n) {
    float s = 0.f;
    for (int cs = 0; cs < CS; ++cs) s += P[(size_t)cs * n + i];
    k[i] = expf(-0.5f * c2 * s);
  }
}

// epilogue: out[i] = relu(bias[c] + sum_cs P[cs*n+i])
__global__ __launch_bounds__(256) void sum_relu_k(
    const float* __restrict__ P, const float* __restrict__ bias,
    float* __restrict__ out, int C, int HW, int n, int CS)
{
  int i = blockIdx.x * 256 + threadIdx.x;
  if (i < n) {
    float s = 0.f;
    for (int cs = 0; cs < CS; ++cs) s += P[(size_t)cs * n + i];
    int c = (i / HW) % C;
    out[i] = fmaxf(s + bias[c], 0.f);
  }
}

// weight transpose: [Cout][Cin][3][3] -> [Cin][9][Cout], all 14 layers
struct TPack {
  const float* src[14];
  float* dst[14];
  int ci[14];
  int co[14];
};

__global__ __launch_bounds__(256) void transpose_w(TPack p)
{
  for (int l = 0; l < 14; ++l) {
    const int ci = p.ci[l], co = p.co[l];
    const int n = ci * co * 9;
    const float* s = p.src[l];
    float* d = p.dst[l];
    for (int idx = blockIdx.x * 256 + threadIdx.x; idx < n;
         idx += gridDim.x * 256) {
      int c = idx / (9 * co);
      int rem = idx - c * 9 * co;
      int t = rem / co;
      int oc = rem - t * co;
      d[idx] = s[((size_t)oc * ci + c) * 9 + t];
    }
  }
}

// ---------------------------------------------------------------------------
extern "C" void kernel_launch(void* const* d_in, const int* in_sizes, int n_in,
                              void* d_out, int out_size, void* d_ws, size_t ws_size,
                              hipStream_t stream)
{
  (void)in_sizes; (void)n_in; (void)out_size;
  const float* x = (const float*)d_in[0];
  const float* Wp[14];
  const float* Bp[14];
  for (int l = 0; l < 14; ++l) {
    Wp[l] = (const float*)d_in[1 + 2 * l];
    Bp[l] = (const float*)d_in[2 + 2 * l];
  }
  float* out = (float*)d_out;
  float* ws  = (float*)d_ws;

  float* A  = ws + OFF_A;
  float* Bf = ws + OFF_B;
  float* P  = ws + OFF_P;
  float* WT = ws + OFF_WT;

  const int ci[14] = {1,64,64, 64,128,128, 128,256,256, 256,512,512, 512,1024};
  const int co[14] = {64,64,64, 128,128,128, 256,256,256, 512,512,512, 1024,1024};

  const int wmode = (ws_size >= (size_t)WS_FULL_FLOATS * 4) ? 1 : 0;

  const float* wl[14];
  if (wmode) {
    size_t off = 0;
    TPack tp;
    for (int l = 0; l < 14; ++l) {
      tp.src[l] = Wp[l];
      tp.dst[l] = WT + off;
      tp.ci[l] = ci[l];
      tp.co[l] = co[l];
      wl[l] = WT + off;
      off += (size_t)ci[l] * co[l] * 9;
    }
    transpose_w<<<2048, 256, 0, stream>>>(tp);
  } else {
    for (int l = 0; l < 14; ++l) wl[l] = Wp[l];
  }

  float* h1 = out + O_H1;
  float* h2 = out + O_H2;
  float* h3 = out + O_H3;
  float* h4 = out + O_H4;
  float* h5 = out + O_H5;
  float* k2 = out + O_K2;
  float* k3 = out + O_K3;
  float* k4 = out + O_K4;
  float* k5 = out + O_K5;

  auto epi = [&](const float* p, const float* bias, float* dst, int C, int HWo, int CS) {
    int n = 2 * C * HWo;
    sum_relu_k<<<(n + 255) / 256, 256, 0, stream>>>(p, bias, dst, C, HWo, n, CS);
  };
  auto pac = [&](const float* g, float* kdst, int C, int H, int CS, float c2) {
    dim3 g1((H / 16) * (H / 16), 2 * CS);
    pac_s1<4><<<g1, 256, 0, stream>>>(g, P, C, H, H, CS);
    int n = 2 * 9 * H * H;
    pac_sum_exp<<<(n + 255) / 256, 256, 0, stream>>>(P, kdst, c2, n, CS);
  };

#define CONV(Sv, HKv, PSv, KCv, TWv, OCBv, src, wi, kern, dst, Cin, Cout, H, CS)  \
  do {                                                                            \
    const int OH_ = (H) / (Sv), TH_ = 256 / (TWv);                                \
    dim3 g_((OH_ / TH_) * (OH_ / (TWv)), (Cout) / (OCBv), 2 * (CS));              \
    conv3x3_k<Sv, HKv, PSv, KCv, TWv, OCBv><<<g_, 256, 0, stream>>>(              \
        src, wl[wi], wmode, Bp[wi], kern, dst, Cin, Cout, H, CS);                 \
  } while (0)

  // ---- stage 1 ----
  CONV(1,0,0,1,32,64, x,  0, nullptr, A,  1,  64, 256, 1);     // 1_1 -> A
  CONV(1,0,0,8,32,64, A,  1, nullptr, h1, 64, 64, 256, 1);     // 1_2 -> h1
  CONV(2,0,1,4,32,32, h1, 2, nullptr, P, 64, 64, 256, 2);      // 1_3 partial
  epi(P, Bp[2], Bf, 64, 128 * 128, 2);                         //   -> Bf

  pac(Bf, k2, 64, 128, 8, 1e-8f);                              // k2

  CONV(1,1,0,8,32,32, Bf, 3, k2, A,  64, 128, 128, 1);         // 2_1 -> A
  CONV(1,1,0,8,32,32, A,  4, k2, h2, 128, 128, 128, 1);        // 2_2 -> h2
  CONV(2,1,1,4,32,32, h2, 5, k2, P, 128, 128, 128, 4);         // 2_3 partial
  epi(P, Bp[5], Bf, 128, 64 * 64, 4);                          //   -> Bf

  pac(Bf, k3, 128, 64, 16, 1e-8f);                             // k3

  CONV(1,1,1,8,32,32, Bf, 6, k3, P, 128, 256, 64, 2);          // 3_1 partial
  epi(P, Bp[6], A, 256, 64 * 64, 2);                           //   -> A
  CONV(1,1,1,8,32,32, A,  7, k3, P, 256, 256, 64, 2);          // 3_2 partial
  epi(P, Bp[7], h3, 256, 64 * 64, 2);                          //   -> h3
  CONV(2,1,1,4,32,32, h3, 8, k3, P, 256, 256, 64, 8);          // 3_3 partial
  epi(P, Bp[8], Bf, 256, 32 * 32, 8);                          //   -> Bf

  pac(Bf, k4, 256, 32, 64, 4.0f);                              // k4 (coeff 2)

  CONV(1,1,1,8,32,32, Bf, 9,  k4, P, 256, 512, 32, 4);         // 4_1 partial
  epi(P, Bp[9], A, 512, 32 * 32, 4);                           //   -> A
  CONV(1,1,1,8,32,32, A,  10, k4, P, 512, 512, 32, 4);         // 4_2 partial
  epi(P, Bp[10], h4, 512, 32 * 32, 4);                         //   -> h4
  CONV(2,1,1,4,16,32, h4, 11, k4, P, 512, 512, 32, 16);        // 4_3 partial
  epi(P, Bp[11], Bf, 512, 16 * 16, 16);                        //   -> Bf

  pac(Bf, k5, 512, 16, 128, 1e-8f);                            // k5

  CONV(1,1,1,8,16,32, Bf, 12, k5, P, 512, 1024, 16, 8);        // 5_1 partial
  epi(P, Bp[12], A, 1024, 16 * 16, 8);                         //   -> A
  CONV(1,1,1,8,16,32, A,  13, k5, P, 1024, 1024, 16, 8);       // 5_2 partial
  epi(P, Bp[13], h5, 1024, 16 * 16, 8);                        //   -> h5

#undef CONV
}

// Round 5
// 1675.941 us; speedup vs baseline: 3.1398x; 1.6143x over previous
//
#include <hip/hip_runtime.h>

typedef float f4 __attribute__((ext_vector_type(4)));
typedef float f2 __attribute__((ext_vector_type(2)));
typedef short bh8 __attribute__((ext_vector_type(8)));   // 8 bf16 in 4 VGPRs
typedef unsigned short ushort_t;
typedef unsigned int uint_t;

// ---------------- workspace layout (float offsets) ----------------
enum : size_t {
  OFF_A  = 0,           // 8,388,608 floats  ping buffer
  OFF_B  = 8388608,     // 4,194,304 floats  pong buffer
  OFF_P  = 12582912,    // 4,194,304 floats  partial sums (conv + pac)
  OFF_WT = 17072128,    // fp32 transposed weights for VALU layers (3,134,016 fl)
  OFF_WH = 20206144,    // hi-plane bf16 weights (18,837,504 ushorts = 9,418,752 fl)
  OFF_WL = 29624896,    // lo-plane bf16 weights
  WS_FULL_FLOATS = 39043648,
};

// ---------------- d_out layout (float offsets), return order ----------------
enum : size_t {
  O_H1 = 0,          // [2,64,256,256]
  O_H2 = 8388608,    // [2,128,128,128]
  O_H3 = 12582912,   // [2,256,64,64]
  O_H4 = 14680064,   // [2,512,32,32]
  O_H5 = 15728640,   // [2,1024,16,16]
  O_K2 = 16252928,   // [2,9,128,128]
  O_K3 = 16547840,   // [2,9,64,64]
  O_K4 = 16621568,   // [2,9,32,32]
  O_K5 = 16640000,   // [2,9,16,16]
};

// ===========================================================================
// MFMA conv 3x3, stride 1, pad 1. Split-bf16 (hi/lo) x 3-term accumulate.
// Block 256 thr = 4 waves (2 wm x 2 wn). Block tile: M = 64 px (4 h x 16 w),
// N = 2*NF*16 oc. Wave: 2 M-frags (h rows) x NF N-frags. Per-tap GEMM over
// c-chunks of 32. A staged fp32 in LDS [6h][18w][44c-pad]; B (weights) read
// directly from global hi/lo planes [t][oc][c] bf16.
// PS=1: write partials to dst + cs*osz (summed by epilogue).
// ===========================================================================
template<int HK, int PS, int NF>
__global__ __launch_bounds__(256) void conv_mfma_k(
    const float* __restrict__ src, const ushort_t* __restrict__ whi,
    const ushort_t* __restrict__ wlo, const float* __restrict__ bias,
    const float* __restrict__ kern, float* __restrict__ dst,
    int Cin, int Cout, int H, int CS)
{
  const int W = H, HW = H * W;
  const int tid  = threadIdx.x;
  const int wave = tid >> 6, lane = tid & 63;
  const int wm = wave >> 1, wn = wave & 1;
  const int l15 = lane & 15, l4 = lane >> 4;
  const int tiles_w = W >> 4;
  const int h0 = (blockIdx.x / tiles_w) * 4;
  const int w0 = (blockIdx.x % tiles_w) * 16;
  const int ocb = blockIdx.y * (32 * NF);
  const int bz = blockIdx.z;
  const int b = bz / CS, cs = bz - b * CS;
  const int CinS = Cin / CS, c_base = cs * CinS;

  __shared__ __align__(16) float xs[6 * 18 * 44];   // (h*18+w)*44 + c

  f4 acc[2][NF];
#pragma unroll
  for (int mf = 0; mf < 2; ++mf)
#pragma unroll
    for (int nf = 0; nf < NF; ++nf) acc[mf][nf] = f4{0.f, 0.f, 0.f, 0.f};

  float kf[2][9];
  if (HK) {
#pragma unroll
    for (int mf = 0; mf < 2; ++mf)
#pragma unroll
      for (int t = 0; t < 9; ++t)
        kf[mf][t] = kern[((size_t)(b * 9 + t) * H + (h0 + wm * 2 + mf)) * W
                         + w0 + l15];
  }

  int ocn[NF];
#pragma unroll
  for (int nf = 0; nf < NF; ++nf) ocn[nf] = ocb + wn * (NF * 16) + nf * 16 + l15;

  const float* sb = src + (size_t)b * Cin * HW;

  for (int c0 = c_base; c0 < c_base + CinS; c0 += 32) {
    __syncthreads();
    // ---- stage interior: 768 f4-loads (w-aligned), scatter to [h][w][c] ----
#pragma unroll
    for (int it = 0; it < 3; ++it) {
      int idx = tid + it * 256;            // exactly 768 total
      int wg = idx & 3, hh = (idx >> 2) % 6, c = idx / 24;
      int hg = h0 + hh - 1;
      f4 v = f4{0.f, 0.f, 0.f, 0.f};
      if (hg >= 0 && hg < H)
        v = *(const f4*)(sb + (size_t)(c0 + c) * HW + (size_t)hg * W + w0 + wg * 4);
#pragma unroll
      for (int i = 0; i < 4; ++i)
        xs[(hh * 18 + wg * 4 + 1 + i) * 44 + c] = v[i];
    }
    // ---- stage edges (w0-1 and w0+16): 384 scalars ----
#pragma unroll
    for (int it = 0; it < 2; ++it) {
      int idx = tid + it * 256;
      if (idx < 384) {
        int side = idx & 1, hh = (idx >> 1) % 6, c = idx / 12;
        int hg = h0 + hh - 1;
        int wgl = side ? (w0 + 16) : (w0 - 1);
        float v = 0.f;
        if (hg >= 0 && hg < H && wgl >= 0 && wgl < W)
          v = sb[(size_t)(c0 + c) * HW + (size_t)hg * W + wgl];
        xs[(hh * 18 + (side ? 17 : 0)) * 44 + c] = v;
      }
    }
    __syncthreads();

    // ---- 9 taps ----
#pragma unroll
    for (int t = 0; t < 9; ++t) {
      const int di = t / 3, dj = t % 3;
      bh8 bh[NF], bl[NF];
#pragma unroll
      for (int nf = 0; nf < NF; ++nf) {
        size_t wo = ((size_t)t * Cout + ocn[nf]) * Cin + c0 + l4 * 8;
        bh[nf] = *(const bh8*)(whi + wo);
        bl[nf] = *(const bh8*)(wlo + wo);
      }
#pragma unroll
      for (int mf = 0; mf < 2; ++mf) {
        const float* xp = &xs[(((wm * 2 + mf) + di) * 18 + l15 + dj) * 44 + l4 * 8];
        f4 x0 = *(const f4*)xp;
        f4 x1 = *(const f4*)(xp + 4);
        float e[8];
#pragma unroll
        for (int j = 0; j < 4; ++j) { e[j] = x0[j]; e[4 + j] = x1[j]; }
        if (HK) {
          const float s = kf[mf][t];
#pragma unroll
          for (int j = 0; j < 8; ++j) e[j] *= s;
        }
        union { uint_t u[4]; bh8 v; } ah, al;
#pragma unroll
        for (int r = 0; r < 4; ++r) {
          uint_t u0 = __float_as_uint(e[2 * r]);
          uint_t u1 = __float_as_uint(e[2 * r + 1]);
          uint_t h0b = u0 & 0xffff0000u;
          uint_t h1b = u1 & 0xffff0000u;
          float l0 = e[2 * r]     - __uint_as_float(h0b);
          float l1 = e[2 * r + 1] - __uint_as_float(h1b);
          ah.u[r] = (h0b >> 16) | h1b;
          al.u[r] = (__float_as_uint(l0) >> 16) | (__float_as_uint(l1) & 0xffff0000u);
        }
#pragma unroll
        for (int nf = 0; nf < NF; ++nf) {
          acc[mf][nf] = __builtin_amdgcn_mfma_f32_16x16x32_bf16(ah.v, bh[nf], acc[mf][nf], 0, 0, 0);
          acc[mf][nf] = __builtin_amdgcn_mfma_f32_16x16x32_bf16(ah.v, bl[nf], acc[mf][nf], 0, 0, 0);
          acc[mf][nf] = __builtin_amdgcn_mfma_f32_16x16x32_bf16(al.v, bh[nf], acc[mf][nf], 0, 0, 0);
        }
      }
    }
  }

  // ---- writeback: lane holds oc = ocn[nf], w = w0 + l4*4 + r ----
  const size_t osz = (size_t)2 * Cout * HW;
#pragma unroll
  for (int mf = 0; mf < 2; ++mf) {
    const int h = h0 + wm * 2 + mf;
#pragma unroll
    for (int nf = 0; nf < NF; ++nf) {
      const int oc = ocn[nf];
      float* op = dst + (PS ? (size_t)cs * osz : 0)
                + ((size_t)(b * Cout + oc) * H + h) * W + w0 + l4 * 4;
      f4 r = acc[mf][nf];
      if (!PS) {
        const float bo = bias[oc];
#pragma unroll
        for (int j = 0; j < 4; ++j) r[j] = fmaxf(r[j] + bo, 0.f);
      }
      *(f4*)op = r;
    }
  }
}

// ===========================================================================
// VALU conv (R4, unchanged) — used for 1_1, strided layers, and fallback.
// ===========================================================================
template<int S, int HK, int PS, int KC, int TW, int OCB>
__global__ __launch_bounds__(256, 2) void conv3x3_k(
    const float* __restrict__ src, const float* __restrict__ wsrc, int wmode,
    const float* __restrict__ bias, const float* __restrict__ kern,
    float* __restrict__ dst, int Cin, int Cout, int H, int CS)
{
  constexpr int TH  = 256 / TW;
  constexpr int RH  = TH * S + 2;
  constexpr int RW  = TW * S + 2;
  constexpr int RW4 = (RW + 3) & ~3;
  constexpr int RWs = (RW4 % 8 == 0) ? RW4 + 4 : RW4;
  constexpr int CPT = TW / 8;
  constexpr int OPT = OCB / 8;
  constexpr int TOTX = KC * RH * RW;
  constexpr int NLX  = (TOTX + 255) / 256;
  constexpr int TOTW = KC * 9 * OCB;
  constexpr int NLW  = (TOTW + 255) / 256;

  __shared__ __align__(16) float xs[KC][RH][RWs];
  __shared__ __align__(16) float wsm[KC][9][OCB];

  const int W = H, HW = H * W;
  const int OH = H / S, OW = W / S;
  const int tid  = threadIdx.x;
  const int ocg  = tid >> 5;
  const int pxg  = tid & 31;
  const int prow = pxg / CPT;
  const int pcol = (pxg % CPT) * 8;
  const int tiles_w = OW / TW;
  const int th0 = (blockIdx.x / tiles_w) * TH;
  const int tw0 = (blockIdx.x % tiles_w) * TW;
  const int ocb = blockIdx.y * OCB;
  const int bz  = blockIdx.z;
  const int b   = bz / CS, cs = bz - b * CS;
  const int CinS   = Cin / CS;
  const int c_base = cs * CinS;
  const int c_end  = c_base + CinS;
  const int oh  = th0 + prow;
  const int ow0 = tw0 + pcol;
  const int oc0 = ocb + ocg * OPT;

  float acc[OPT][8];
#pragma unroll
  for (int o = 0; o < OPT; ++o)
#pragma unroll
    for (int p = 0; p < 8; ++p) acc[o][p] = 0.f;

  float kf[HK ? 9 : 1][8];
  if (HK) {
#pragma unroll
    for (int t = 0; t < 9; ++t) {
      const float* kp = kern + ((size_t)(b * 9 + t) * H + (size_t)oh * S) * W
                             + (size_t)ow0 * S;
      if constexpr (S == 1) {
        f4 a = *(const f4*)kp; f4 c = *(const f4*)(kp + 4);
#pragma unroll
        for (int p = 0; p < 4; ++p) { kf[t][p] = a[p]; kf[t][4 + p] = c[p]; }
      } else {
#pragma unroll
        for (int p = 0; p < 8; ++p) kf[t][p] = kp[2 * p];
      }
    }
  }

  const float* xb = src + (size_t)b * Cin * HW;

  float xr[NLX], wr[NLW];

  auto loadX = [&](int c0) {
#pragma unroll
    for (int l = 0; l < NLX; ++l) {
      const int idx = tid + l * 256;
      float v = 0.f;
      if (idx < TOTX) {
        int kc  = idx / (RH * RW);
        int rem = idx - kc * (RH * RW);
        int r   = rem / RW;
        int col = rem - r * RW;
        int ih = th0 * S + r - 1;
        int iw = tw0 * S + col - 1;
        if (ih >= 0 && ih < H && iw >= 0 && iw < W)
          v = xb[(size_t)(c0 + kc) * HW + (size_t)ih * W + iw];
      }
      xr[l] = v;
    }
  };
  auto storeX = [&]() {
#pragma unroll
    for (int l = 0; l < NLX; ++l) {
      const int idx = tid + l * 256;
      if (idx < TOTX) {
        int kc  = idx / (RH * RW);
        int rem = idx - kc * (RH * RW);
        int r   = rem / RW;
        int col = rem - r * RW;
        xs[kc][r][col] = xr[l];
      }
    }
  };
  auto loadW = [&](int c0) {
#pragma unroll
    for (int l = 0; l < NLW; ++l) {
      const int idx = tid + l * 256;
      if (idx < TOTW) {
        int kc  = idx / (9 * OCB);
        int rem = idx - kc * (9 * OCB);
        int t   = rem / OCB;
        int o   = rem - t * OCB;
        wr[l] = wmode
          ? wsrc[((size_t)(c0 + kc) * 9 + t) * Cout + ocb + o]
          : wsrc[((size_t)(ocb + o) * Cin + (c0 + kc)) * 9 + t];
      }
    }
  };
  auto storeW = [&]() {
#pragma unroll
    for (int l = 0; l < NLW; ++l) {
      const int idx = tid + l * 256;
      if (idx < TOTW) {
        int kc  = idx / (9 * OCB);
        int rem = idx - kc * (9 * OCB);
        int t   = rem / OCB;
        int o   = rem - t * OCB;
        wsm[kc][t][o] = wr[l];
      }
    }
  };

  loadX(c_base);
  loadW(c_base);

  for (int c0 = c_base; c0 < c_end; c0 += KC) {
    storeX();
    storeW();
    __syncthreads();
    if (c0 + KC < c_end) { loadX(c0 + KC); loadW(c0 + KC); }

#pragma unroll 1
    for (int kc = 0; kc < KC; ++kc) {
#pragma unroll
      for (int di = 0; di < 3; ++di) {
        const float* xrow = &xs[kc][prow * S + di][pcol * S];
        f4 xa, xbv, xc, xd; f2 xe2; float xe;
        xa  = *(const f4*)xrow;
        xbv = *(const f4*)(xrow + 4);
        if constexpr (S == 1) {
          xe2 = *(const f2*)(xrow + 8);
        } else {
          xc = *(const f4*)(xrow + 8);
          xd = *(const f4*)(xrow + 12);
          xe = xrow[16];
        }
        auto xget = [&](int q) -> float {
          if constexpr (S == 1)
            return (q < 4) ? xa[q] : (q < 8) ? xbv[q - 4] : xe2[q - 8];
          else
            return (q < 4) ? xa[q] : (q < 8) ? xbv[q - 4]
                 : (q < 12) ? xc[q - 8] : (q < 16) ? xd[q - 12] : xe;
        };

#pragma unroll
        for (int dj = 0; dj < 3; ++dj) {
          const int t = di * 3 + dj;
          f4 wv[OPT / 4 > 0 ? OPT / 4 : 1];
#pragma unroll
          for (int u = 0; u < OPT / 4; ++u)
            wv[u] = *(const f4*)&wsm[kc][t][ocg * OPT + 4 * u];

          float xq[8];
#pragma unroll
          for (int p = 0; p < 8; ++p) {
            float xvv = xget(S * p + dj);
            xq[p] = HK ? xvv * kf[t][p] : xvv;
          }
#pragma unroll
          for (int o = 0; o < OPT; ++o) {
            const float w = wv[o >> 2][o & 3];
#pragma unroll
            for (int p = 0; p < 8; ++p)
              acc[o][p] = fmaf(w, xq[p], acc[o][p]);
          }
        }
      }
    }
    __syncthreads();
  }

  const size_t osz = (size_t)2 * Cout * OH * OW;
#pragma unroll
  for (int o = 0; o < OPT; ++o) {
    const int oc = oc0 + o;
    float* orow = dst + (PS ? (size_t)cs * osz : 0)
                + ((size_t)b * Cout + oc) * OH * OW + (size_t)oh * OW + ow0;
    f4 r0, r1;
    if constexpr (PS) {
#pragma unroll
      for (int p = 0; p < 4; ++p) { r0[p] = acc[o][p]; r1[p] = acc[o][4 + p]; }
    } else {
      const float bo = bias[oc];
#pragma unroll
      for (int p = 0; p < 4; ++p) {
        r0[p] = fmaxf(acc[o][p] + bo, 0.f);
        r1[p] = fmaxf(acc[o][4 + p] + bo, 0.f);
      }
    }
    *(f4*)orow = r0; *(f4*)(orow + 4) = r1;
  }
}

// ---------------------------------------------------------------------------
// PAC stage 1 (partial sums per channel-slice)
// ---------------------------------------------------------------------------
template<int KCC>
__global__ __launch_bounds__(256) void pac_s1(
    const float* __restrict__ g, float* __restrict__ s,
    int C, int H, int W, int CS)
{
  __shared__ float xs[KCC][18][19];
  const int tid = threadIdx.x;
  const int pr = tid >> 4, pc = tid & 15;
  const int tiles_w = W / 16;
  const int tile = blockIdx.x;
  const int th0 = (tile / tiles_w) * 16, tw0 = (tile % tiles_w) * 16;
  const int bz = blockIdx.y;
  const int b = bz / CS, cs = bz - b * CS;
  const int CinS = C / CS, c0b = cs * CinS;

  float acc[9];
#pragma unroll
  for (int t = 0; t < 9; ++t) acc[t] = 0.f;

  const float* gb = g + (size_t)b * C * H * W;
  for (int c0 = c0b; c0 < c0b + CinS; c0 += KCC) {
    for (int idx = tid; idx < KCC * 18 * 18; idx += 256) {
      int kc = idx / 324;
      int rem = idx - kc * 324;
      int r = rem / 18, col = rem - r * 18;
      int ih = th0 + r - 1, iw = tw0 + col - 1;
      float v = 0.f;
      if (ih >= 0 && ih < H && iw >= 0 && iw < W)
        v = gb[(size_t)(c0 + kc) * H * W + (size_t)ih * W + iw];
      xs[kc][r][col] = v;
    }
    __syncthreads();
#pragma unroll
    for (int kc = 0; kc < KCC; ++kc) {
      float xcv = xs[kc][pr + 1][pc + 1];
#pragma unroll
      for (int di = 0; di < 3; ++di)
#pragma unroll
        for (int dj = 0; dj < 3; ++dj) {
          float d = xs[kc][pr + di][pc + dj] - xcv;
          acc[di * 3 + dj] = fmaf(d, d, acc[di * 3 + dj]);
        }
    }
    __syncthreads();
  }

  const size_t HWs = (size_t)H * W;
  float* sp = s + ((size_t)(cs * 2 + b) * 9) * HWs
            + (size_t)(th0 + pr) * W + tw0 + pc;
#pragma unroll
  for (int t = 0; t < 9; ++t) sp[t * HWs] = acc[t];
}

__global__ __launch_bounds__(256) void pac_sum_exp(
    const float* __restrict__ P, float* __restrict__ k, float c2, int n, int CS)
{
  int i = blockIdx.x * 256 + threadIdx.x;
  if (i < n) {
    float s = 0.f;
    for (int cs = 0; cs < CS; ++cs) s += P[(size_t)cs * n + i];
    k[i] = expf(-0.5f * c2 * s);
  }
}

__global__ __launch_bounds__(256) void sum_relu_k(
    const float* __restrict__ P, const float* __restrict__ bias,
    float* __restrict__ out, int C, int HW, int n, int CS)
{
  int i = blockIdx.x * 256 + threadIdx.x;
  if (i < n) {
    float s = 0.f;
    for (int cs = 0; cs < CS; ++cs) s += P[(size_t)cs * n + i];
    int c = (i / HW) % C;
    out[i] = fmaxf(s + bias[c], 0.f);
  }
}

// ---------------------------------------------------------------------------
// weight prep
// ---------------------------------------------------------------------------
struct TPack5 {
  const float* src[5];
  float* dst[5];
  int ci[5];
  int co[5];
};

__global__ __launch_bounds__(256) void transpose_w5(TPack5 p)
{
  for (int l = 0; l < 5; ++l) {
    const int ci = p.ci[l], co = p.co[l];
    const int n = ci * co * 9;
    const float* s = p.src[l];
    float* d = p.dst[l];
    for (int idx = blockIdx.x * 256 + threadIdx.x; idx < n;
         idx += gridDim.x * 256) {
      int c = idx / (9 * co);
      int rem = idx - c * 9 * co;
      int t = rem / co;
      int oc = rem - t * co;
      d[idx] = s[((size_t)oc * ci + c) * 9 + t];
    }
  }
}

struct SPack9 {
  const float* src[9];
  int ci[9];
  int co[9];
  size_t off[9];
};

__global__ __launch_bounds__(256) void split_w9(SPack9 p, ushort_t* hi, ushort_t* lo)
{
  for (int l = 0; l < 9; ++l) {
    const int ci = p.ci[l], co = p.co[l];
    const int n = 9 * ci * co;
    const float* s = p.src[l];
    ushort_t* ph = hi + p.off[l];
    ushort_t* pl = lo + p.off[l];
    for (int idx = blockIdx.x * 256 + threadIdx.x; idx < n;
         idx += gridDim.x * 256) {
      int c = idx % ci;
      int r = idx / ci;
      int oc = r % co;
      int t = r / co;
      float w = s[((size_t)oc * ci + c) * 9 + t];
      uint_t u = __float_as_uint(w);
      uint_t hb = u & 0xffff0000u;
      float lov = w - __uint_as_float(hb);
      ph[idx] = (ushort_t)(hb >> 16);
      pl[idx] = (ushort_t)(__float_as_uint(lov) >> 16);
    }
  }
}

// ---------------------------------------------------------------------------
extern "C" void kernel_launch(void* const* d_in, const int* in_sizes, int n_in,
                              void* d_out, int out_size, void* d_ws, size_t ws_size,
                              hipStream_t stream)
{
  (void)in_sizes; (void)n_in; (void)out_size;
  const float* x = (const float*)d_in[0];
  const float* Wp[14];
  const float* Bp[14];
  for (int l = 0; l < 14; ++l) {
    Wp[l] = (const float*)d_in[1 + 2 * l];
    Bp[l] = (const float*)d_in[2 + 2 * l];
  }
  float* out = (float*)d_out;
  float* ws  = (float*)d_ws;

  float*    A   = ws + OFF_A;
  float*    Bf  = ws + OFF_B;
  float*    P   = ws + OFF_P;
  float*    WT  = ws + OFF_WT;
  ushort_t* WHI = (ushort_t*)(ws + OFF_WH);
  ushort_t* WLO = (ushort_t*)(ws + OFF_WL);

  const int ci[14] = {1,64,64, 64,128,128, 128,256,256, 256,512,512, 512,1024};
  const int co[14] = {64,64,64, 128,128,128, 256,256,256, 512,512,512, 1024,1024};

  const int wmode = (ws_size >= (size_t)WS_FULL_FLOATS * 4) ? 1 : 0;

  float* h1 = out + O_H1;
  float* h2 = out + O_H2;
  float* h3 = out + O_H3;
  float* h4 = out + O_H4;
  float* h5 = out + O_H5;
  float* k2 = out + O_K2;
  float* k3 = out + O_K3;
  float* k4 = out + O_K4;
  float* k5 = out + O_K5;

  auto epi = [&](const float* p, const float* bias, float* dst, int C, int HWo, int CS) {
    int n = 2 * C * HWo;
    sum_relu_k<<<(n + 255) / 256, 256, 0, stream>>>(p, bias, dst, C, HWo, n, CS);
  };
  auto pac = [&](const float* g, float* kdst, int C, int H, int CS, float c2) {
    dim3 g1((H / 16) * (H / 16), 2 * CS);
    pac_s1<4><<<g1, 256, 0, stream>>>(g, P, C, H, H, CS);
    int n = 2 * 9 * H * H;
    pac_sum_exp<<<(n + 255) / 256, 256, 0, stream>>>(P, kdst, c2, n, CS);
  };

  if (wmode) {
    // ---- prep: fp32 transpose for 5 VALU layers ----
    const int vidx[5] = {0, 2, 5, 8, 11};
    TPack5 tp;
    const float* wv[5];
    {
      size_t off = 0;
      for (int i = 0; i < 5; ++i) {
        int l = vidx[i];
        tp.src[i] = Wp[l];
        tp.dst[i] = WT + off;
        tp.ci[i] = ci[l];
        tp.co[i] = co[l];
        wv[i] = WT + off;
        off += (size_t)ci[l] * co[l] * 9;
      }
    }
    transpose_w5<<<512, 256, 0, stream>>>(tp);

    // ---- prep: hi/lo bf16 split for 9 MFMA layers ----
    const int midx[9] = {1, 3, 4, 6, 7, 9, 10, 12, 13};
    SPack9 sp;
    size_t moff[9];
    {
      size_t off = 0;
      for (int i = 0; i < 9; ++i) {
        int l = midx[i];
        sp.src[i] = Wp[l];
        sp.ci[i] = ci[l];
        sp.co[i] = co[l];
        sp.off[i] = off;
        moff[i] = off;
        off += (size_t)ci[l] * co[l] * 9;
      }
    }
    split_w9<<<2048, 256, 0, stream>>>(sp, WHI, WLO);

#define CONV_V(Sv, HKv, PSv, KCv, TWv, OCBv, src_, wptr, bptr, kern_, dst_, Cin_, Cout_, H_, CS_) \
    do {                                                                          \
      const int OH_ = (H_) / (Sv), TH_ = 256 / (TWv);                             \
      dim3 g_((OH_ / TH_) * (OH_ / (TWv)), (Cout_) / (OCBv), 2 * (CS_));          \
      conv3x3_k<Sv, HKv, PSv, KCv, TWv, OCBv><<<g_, 256, 0, stream>>>(            \
          src_, wptr, 1, bptr, kern_, dst_, Cin_, Cout_, H_, CS_);                \
    } while (0)

#define CONV_M(HKv, PSv, NFv, src_, mi, li, kern_, dst_, Cin_, Cout_, H_, CS_)    \
    do {                                                                          \
      dim3 g_(((H_) / 4) * ((H_) / 16), (Cout_) / (32 * (NFv)), 2 * (CS_));       \
      conv_mfma_k<HKv, PSv, NFv><<<g_, 256, 0, stream>>>(                         \
          src_, WHI + moff[mi], WLO + moff[mi], Bp[li], kern_, dst_,              \
          Cin_, Cout_, H_, CS_);                                                  \
    } while (0)

    // ---- stage 1 ----
    CONV_V(1,0,0,1,32,64, x, wv[0], Bp[0], nullptr, A, 1, 64, 256, 1);     // 1_1
    CONV_M(0,0,2, A, 0, 1, nullptr, h1, 64, 64, 256, 1);                   // 1_2
    CONV_V(2,0,1,4,32,32, h1, wv[1], nullptr, nullptr, P, 64, 64, 256, 2); // 1_3
    epi(P, Bp[2], Bf, 64, 128 * 128, 2);

    pac(Bf, k2, 64, 128, 8, 1e-8f);

    CONV_M(1,0,4, Bf, 1, 3, k2, A,  64, 128, 128, 1);                      // 2_1
    CONV_M(1,0,4, A,  2, 4, k2, h2, 128, 128, 128, 1);                     // 2_2
    CONV_V(2,1,1,4,32,32, h2, wv[2], nullptr, k2, P, 128, 128, 128, 4);    // 2_3
    epi(P, Bp[5], Bf, 128, 64 * 64, 4);

    pac(Bf, k3, 128, 64, 16, 1e-8f);

    CONV_M(1,0,4, Bf, 3, 6, k3, A,  128, 256, 64, 1);                      // 3_1
    CONV_M(1,0,4, A,  4, 7, k3, h3, 256, 256, 64, 1);                      // 3_2
    CONV_V(2,1,1,4,32,32, h3, wv[3], nullptr, k3, P, 256, 256, 64, 8);     // 3_3
    epi(P, Bp[8], Bf, 256, 32 * 32, 8);

    pac(Bf, k4, 256, 32, 64, 4.0f);

    CONV_M(1,1,4, Bf, 5, 9, k4, P, 256, 512, 32, 2);                       // 4_1
    epi(P, Bp[9], A, 512, 32 * 32, 2);
    CONV_M(1,1,4, A,  6, 10, k4, P, 512, 512, 32, 2);                      // 4_2
    epi(P, Bp[10], h4, 512, 32 * 32, 2);
    CONV_V(2,1,1,4,16,32, h4, wv[4], nullptr, k4, P, 512, 512, 32, 16);    // 4_3
    epi(P, Bp[11], Bf, 512, 16 * 16, 16);

    pac(Bf, k5, 512, 16, 128, 1e-8f);

    CONV_M(1,1,4, Bf, 7, 12, k5, P, 512, 1024, 16, 4);                     // 5_1
    epi(P, Bp[12], A, 1024, 16 * 16, 4);
    CONV_M(1,1,4, A,  8, 13, k5, P, 1024, 1024, 16, 4);                    // 5_2
    epi(P, Bp[13], h5, 1024, 16 * 16, 4);

#undef CONV_V
#undef CONV_M
  } else {
    // ---- fallback: full VALU path with raw weights (R4 structure) ----
#define CONV_R(Sv, HKv, PSv, KCv, TWv, OCBv, src_, wi, kern_, dst_, Cin_, Cout_, H_, CS_) \
    do {                                                                          \
      const int OH_ = (H_) / (Sv), TH_ = 256 / (TWv);                             \
      dim3 g_((OH_ / TH_) * (OH_ / (TWv)), (Cout_) / (OCBv), 2 * (CS_));          \
      conv3x3_k<Sv, HKv, PSv, KCv, TWv, OCBv><<<g_, 256, 0, stream>>>(            \
          src_, Wp[wi], 0, Bp[wi], kern_, dst_, Cin_, Cout_, H_, CS_);            \
    } while (0)

    CONV_R(1,0,0,1,32,64, x,  0, nullptr, A,  1,  64, 256, 1);
    CONV_R(1,0,0,8,32,64, A,  1, nullptr, h1, 64, 64, 256, 1);
    CONV_R(2,0,1,4,32,32, h1, 2, nullptr, P, 64, 64, 256, 2);
    epi(P, Bp[2], Bf, 64, 128 * 128, 2);
    pac(Bf, k2, 64, 128, 8, 1e-8f);
    CONV_R(1,1,0,8,32,32, Bf, 3, k2, A,  64, 128, 128, 1);
    CONV_R(1,1,0,8,32,32, A,  4, k2, h2, 128, 128, 128, 1);
    CONV_R(2,1,1,4,32,32, h2, 5, k2, P, 128, 128, 128, 4);
    epi(P, Bp[5], Bf, 128, 64 * 64, 4);
    pac(Bf, k3, 128, 64, 16, 1e-8f);
    CONV_R(1,1,1,8,32,32, Bf, 6, k3, P, 128, 256, 64, 2);
    epi(P, Bp[6], A, 256, 64 * 64, 2);
    CONV_R(1,1,1,8,32,32, A,  7, k3, P, 256, 256, 64, 2);
    epi(P, Bp[7], h3, 256, 64 * 64, 2);
    CONV_R(2,1,1,4,32,32, h3, 8, k3, P, 256, 256, 64, 8);
    epi(P, Bp[8], Bf, 256, 32 * 32, 8);
    pac(Bf, k4, 256, 32, 64, 4.0f);
    CONV_R(1,1,1,8,32,32, Bf, 9,  k4, P, 256, 512, 32, 4);
    epi(P, Bp[9], A, 512, 32 * 32, 4);
    CONV_R(1,1,1,8,32,32, A,  10, k4, P, 512, 512, 32, 4);
    epi(P, Bp[10], h4, 512, 32 * 32, 4);
    CONV_R(2,1,1,4,16,32, h4, 11, k4, P, 512, 512, 32, 16);
    epi(P, Bp[11], Bf, 512, 16 * 16, 16);
    pac(Bf, k5, 512, 16, 128, 1e-8f);
    CONV_R(1,1,1,8,16,32, Bf, 12, k5, P, 512, 1024, 16, 8);
    epi(P, Bp[12], A, 1024, 16 * 16, 8);
    CONV_R(1,1,1,8,16,32, A,  13, k5, P, 1024, 1024, 16, 8);
    epi(P, Bp[13], h5, 1024, 16 * 16, 8);
#undef CONV_R
  }
}

// Round 6
// 1077.026 us; speedup vs baseline: 4.8857x; 1.5561x over previous
//
#include <hip/hip_runtime.h>

typedef float f4 __attribute__((ext_vector_type(4)));
typedef float f2 __attribute__((ext_vector_type(2)));
typedef short bh8 __attribute__((ext_vector_type(8)));   // 8 bf16 in 4 VGPRs
typedef unsigned short ushort_t;
typedef unsigned int uint_t;

// ---------------- workspace layout (float offsets) ----------------
enum : size_t {
  OFF_A  = 0,           // 8,388,608 floats  ping buffer
  OFF_B  = 8388608,     // 4,194,304 floats  pong buffer
  OFF_P  = 12582912,    // 4,194,304 floats  partial sums (conv + pac)
  OFF_WH = 17072128,    // hi-plane bf16 weights, 13 layers (21,970,944 ushorts)
  OFF_WL = 28057600,    // lo-plane bf16 weights
  WS_FULL_FLOATS = 39043648,   // same check value that passed R4/R5
};

// ---------------- d_out layout (float offsets), return order ----------------
enum : size_t {
  O_H1 = 0,          // [2,64,256,256]
  O_H2 = 8388608,    // [2,128,128,128]
  O_H3 = 12582912,   // [2,256,64,64]
  O_H4 = 14680064,   // [2,512,32,32]
  O_H5 = 15728640,   // [2,1024,16,16]
  O_K2 = 16252928,   // [2,9,128,128]
  O_K3 = 16547840,   // [2,9,64,64]
  O_K4 = 16621568,   // [2,9,32,32]
  O_K5 = 16640000,   // [2,9,16,16]
};

// ===========================================================================
// MFMA conv 3x3 stride 1, pad 1 (R5, validated). Split-bf16 hi/lo, 3 MFMA.
// ===========================================================================
template<int HK, int PS, int NF>
__global__ __launch_bounds__(256) void conv_mfma_k(
    const float* __restrict__ src, const ushort_t* __restrict__ whi,
    const ushort_t* __restrict__ wlo, const float* __restrict__ bias,
    const float* __restrict__ kern, float* __restrict__ dst,
    int Cin, int Cout, int H, int CS)
{
  const int W = H, HW = H * W;
  const int tid  = threadIdx.x;
  const int wave = tid >> 6, lane = tid & 63;
  const int wm = wave >> 1, wn = wave & 1;
  const int l15 = lane & 15, l4 = lane >> 4;
  const int tiles_w = W >> 4;
  const int h0 = (blockIdx.x / tiles_w) * 4;
  const int w0 = (blockIdx.x % tiles_w) * 16;
  const int ocb = blockIdx.y * (32 * NF);
  const int bz = blockIdx.z;
  const int b = bz / CS, cs = bz - b * CS;
  const int CinS = Cin / CS, c_base = cs * CinS;

  __shared__ __align__(16) float xs[6 * 18 * 44];   // (h*18+w)*44 + c

  f4 acc[2][NF];
#pragma unroll
  for (int mf = 0; mf < 2; ++mf)
#pragma unroll
    for (int nf = 0; nf < NF; ++nf) acc[mf][nf] = f4{0.f, 0.f, 0.f, 0.f};

  float kf[2][9];
  if (HK) {
#pragma unroll
    for (int mf = 0; mf < 2; ++mf)
#pragma unroll
      for (int t = 0; t < 9; ++t)
        kf[mf][t] = kern[((size_t)(b * 9 + t) * H + (h0 + wm * 2 + mf)) * W
                         + w0 + l15];
  }

  int ocn[NF];
#pragma unroll
  for (int nf = 0; nf < NF; ++nf) ocn[nf] = ocb + wn * (NF * 16) + nf * 16 + l15;

  const float* sb = src + (size_t)b * Cin * HW;

  for (int c0 = c_base; c0 < c_base + CinS; c0 += 32) {
    __syncthreads();
#pragma unroll
    for (int it = 0; it < 3; ++it) {
      int idx = tid + it * 256;            // 768 f4 loads
      int wg = idx & 3, hh = (idx >> 2) % 6, c = idx / 24;
      int hg = h0 + hh - 1;
      f4 v = f4{0.f, 0.f, 0.f, 0.f};
      if (hg >= 0 && hg < H)
        v = *(const f4*)(sb + (size_t)(c0 + c) * HW + (size_t)hg * W + w0 + wg * 4);
#pragma unroll
      for (int i = 0; i < 4; ++i)
        xs[(hh * 18 + wg * 4 + 1 + i) * 44 + c] = v[i];
    }
#pragma unroll
    for (int it = 0; it < 2; ++it) {
      int idx = tid + it * 256;
      if (idx < 384) {
        int side = idx & 1, hh = (idx >> 1) % 6, c = idx / 12;
        int hg = h0 + hh - 1;
        int wgl = side ? (w0 + 16) : (w0 - 1);
        float v = 0.f;
        if (hg >= 0 && hg < H && wgl >= 0 && wgl < W)
          v = sb[(size_t)(c0 + c) * HW + (size_t)hg * W + wgl];
        xs[(hh * 18 + (side ? 17 : 0)) * 44 + c] = v;
      }
    }
    __syncthreads();

#pragma unroll
    for (int t = 0; t < 9; ++t) {
      const int di = t / 3, dj = t % 3;
      bh8 bh[NF], bl[NF];
#pragma unroll
      for (int nf = 0; nf < NF; ++nf) {
        size_t wo = ((size_t)t * Cout + ocn[nf]) * Cin + c0 + l4 * 8;
        bh[nf] = *(const bh8*)(whi + wo);
        bl[nf] = *(const bh8*)(wlo + wo);
      }
#pragma unroll
      for (int mf = 0; mf < 2; ++mf) {
        const float* xp = &xs[(((wm * 2 + mf) + di) * 18 + l15 + dj) * 44 + l4 * 8];
        f4 x0 = *(const f4*)xp;
        f4 x1 = *(const f4*)(xp + 4);
        float e[8];
#pragma unroll
        for (int j = 0; j < 4; ++j) { e[j] = x0[j]; e[4 + j] = x1[j]; }
        if (HK) {
          const float s = kf[mf][t];
#pragma unroll
          for (int j = 0; j < 8; ++j) e[j] *= s;
        }
        union { uint_t u[4]; bh8 v; } ah, al;
#pragma unroll
        for (int r = 0; r < 4; ++r) {
          uint_t u0 = __float_as_uint(e[2 * r]);
          uint_t u1 = __float_as_uint(e[2 * r + 1]);
          uint_t h0b = u0 & 0xffff0000u;
          uint_t h1b = u1 & 0xffff0000u;
          float l0 = e[2 * r]     - __uint_as_float(h0b);
          float l1 = e[2 * r + 1] - __uint_as_float(h1b);
          ah.u[r] = (h0b >> 16) | h1b;
          al.u[r] = (__float_as_uint(l0) >> 16) | (__float_as_uint(l1) & 0xffff0000u);
        }
#pragma unroll
        for (int nf = 0; nf < NF; ++nf) {
          acc[mf][nf] = __builtin_amdgcn_mfma_f32_16x16x32_bf16(ah.v, bh[nf], acc[mf][nf], 0, 0, 0);
          acc[mf][nf] = __builtin_amdgcn_mfma_f32_16x16x32_bf16(ah.v, bl[nf], acc[mf][nf], 0, 0, 0);
          acc[mf][nf] = __builtin_amdgcn_mfma_f32_16x16x32_bf16(al.v, bh[nf], acc[mf][nf], 0, 0, 0);
        }
      }
    }
  }

  const size_t osz = (size_t)2 * Cout * HW;
#pragma unroll
  for (int mf = 0; mf < 2; ++mf) {
    const int h = h0 + wm * 2 + mf;
#pragma unroll
    for (int nf = 0; nf < NF; ++nf) {
      const int oc = ocn[nf];
      float* op = dst + (PS ? (size_t)cs * osz : 0)
                + ((size_t)(b * Cout + oc) * H + h) * W + w0 + l4 * 4;
      f4 r = acc[mf][nf];
      if (!PS) {
        const float bo = bias[oc];
#pragma unroll
        for (int j = 0; j < 4; ++j) r[j] = fmaxf(r[j] + bo, 0.f);
      }
      *(f4*)op = r;
    }
  }
}

// ===========================================================================
// MFMA conv 3x3 stride 2, pad 1. Same math; A-fragment reads LDS col 2*l15+dj
// and PAC factors are gathered at input-grid coords (2h, 2w).
// Input tile per block: 10 rows x 33 cols (col 0 = left edge) x 32 ch.
// LDS [10][34][36] fp32 = 49 KB.
// ===========================================================================
template<int HK, int PS, int NF>
__global__ __launch_bounds__(256) void conv_mfma_s2_k(
    const float* __restrict__ src, const ushort_t* __restrict__ whi,
    const ushort_t* __restrict__ wlo, const float* __restrict__ bias,
    const float* __restrict__ kern, float* __restrict__ dst,
    int Cin, int Cout, int H, int CS)
{
  const int W = H, HW = H * W;
  const int OH = H >> 1, OW = W >> 1;
  const int tid  = threadIdx.x;
  const int wave = tid >> 6, lane = tid & 63;
  const int wm = wave >> 1, wn = wave & 1;
  const int l15 = lane & 15, l4 = lane >> 4;
  const int tiles_w = OW >> 4;
  const int h0  = (blockIdx.x / tiles_w) * 4;    // output row base
  const int ow0 = (blockIdx.x % tiles_w) * 16;   // output col base
  const int iw0 = ow0 * 2;                       // input col base (32-aligned)
  const int ihb = h0 * 2 - 1;                    // input row base (row_local 0)
  const int ocb = blockIdx.y * (32 * NF);
  const int bz = blockIdx.z;
  const int b = bz / CS, cs = bz - b * CS;
  const int CinS = Cin / CS, c_base = cs * CinS;

  __shared__ __align__(16) float xs[10 * 34 * 36];   // (hh*34+wl)*36 + c

  f4 acc[2][NF];
#pragma unroll
  for (int mf = 0; mf < 2; ++mf)
#pragma unroll
    for (int nf = 0; nf < NF; ++nf) acc[mf][nf] = f4{0.f, 0.f, 0.f, 0.f};

  float kf[2][9];
  if (HK) {
#pragma unroll
    for (int mf = 0; mf < 2; ++mf)
#pragma unroll
      for (int t = 0; t < 9; ++t)
        kf[mf][t] = kern[((size_t)(b * 9 + t) * H + 2 * (h0 + wm * 2 + mf)) * W
                         + iw0 + 2 * l15];
  }

  int ocn[NF];
#pragma unroll
  for (int nf = 0; nf < NF; ++nf) ocn[nf] = ocb + wn * (NF * 16) + nf * 16 + l15;

  const float* sb = src + (size_t)b * Cin * HW;

  for (int c0 = c_base; c0 < c_base + CinS; c0 += 32) {
    __syncthreads();
    // interior: 10 rows x 8 f4-groups (cols iw0..iw0+31) x 32 ch = 2560 f4
#pragma unroll
    for (int it = 0; it < 10; ++it) {
      int idx = tid + it * 256;
      int wg = idx & 7, hh = (idx >> 3) % 10, c = idx / 80;
      int ih = ihb + hh;
      f4 v = f4{0.f, 0.f, 0.f, 0.f};
      if (ih >= 0 && ih < H)
        v = *(const f4*)(sb + (size_t)(c0 + c) * HW + (size_t)ih * W + iw0 + wg * 4);
#pragma unroll
      for (int i = 0; i < 4; ++i)
        xs[(hh * 34 + 1 + wg * 4 + i) * 36 + c] = v[i];
    }
    // left edge col iw0-1 -> wl=0: 10 x 32 = 320 scalars
#pragma unroll
    for (int it = 0; it < 2; ++it) {
      int idx = tid + it * 256;
      if (idx < 320) {
        int hh = idx % 10, c = idx / 10;
        int ih = ihb + hh;
        float v = 0.f;
        if (ih >= 0 && ih < H && iw0 > 0)
          v = sb[(size_t)(c0 + c) * HW + (size_t)ih * W + iw0 - 1];
        xs[(hh * 34) * 36 + c] = v;
      }
    }
    __syncthreads();

#pragma unroll
    for (int t = 0; t < 9; ++t) {
      const int di = t / 3, dj = t % 3;
      bh8 bh[NF], bl[NF];
#pragma unroll
      for (int nf = 0; nf < NF; ++nf) {
        size_t wo = ((size_t)t * Cout + ocn[nf]) * Cin + c0 + l4 * 8;
        bh[nf] = *(const bh8*)(whi + wo);
        bl[nf] = *(const bh8*)(wlo + wo);
      }
#pragma unroll
      for (int mf = 0; mf < 2; ++mf) {
        // input row_local = 2*(output h offset) + di ; col_local = 2*l15 + dj
        const float* xp = &xs[((2 * (wm * 2 + mf) + di) * 34 + 2 * l15 + dj) * 36 + l4 * 8];
        f4 x0 = *(const f4*)xp;
        f4 x1 = *(const f4*)(xp + 4);
        float e[8];
#pragma unroll
        for (int j = 0; j < 4; ++j) { e[j] = x0[j]; e[4 + j] = x1[j]; }
        if (HK) {
          const float s = kf[mf][t];
#pragma unroll
          for (int j = 0; j < 8; ++j) e[j] *= s;
        }
        union { uint_t u[4]; bh8 v; } ah, al;
#pragma unroll
        for (int r = 0; r < 4; ++r) {
          uint_t u0 = __float_as_uint(e[2 * r]);
          uint_t u1 = __float_as_uint(e[2 * r + 1]);
          uint_t h0b = u0 & 0xffff0000u;
          uint_t h1b = u1 & 0xffff0000u;
          float l0 = e[2 * r]     - __uint_as_float(h0b);
          float l1 = e[2 * r + 1] - __uint_as_float(h1b);
          ah.u[r] = (h0b >> 16) | h1b;
          al.u[r] = (__float_as_uint(l0) >> 16) | (__float_as_uint(l1) & 0xffff0000u);
        }
#pragma unroll
        for (int nf = 0; nf < NF; ++nf) {
          acc[mf][nf] = __builtin_amdgcn_mfma_f32_16x16x32_bf16(ah.v, bh[nf], acc[mf][nf], 0, 0, 0);
          acc[mf][nf] = __builtin_amdgcn_mfma_f32_16x16x32_bf16(ah.v, bl[nf], acc[mf][nf], 0, 0, 0);
          acc[mf][nf] = __builtin_amdgcn_mfma_f32_16x16x32_bf16(al.v, bh[nf], acc[mf][nf], 0, 0, 0);
        }
      }
    }
  }

  const size_t osz = (size_t)2 * Cout * OH * OW;
#pragma unroll
  for (int mf = 0; mf < 2; ++mf) {
    const int h = h0 + wm * 2 + mf;
#pragma unroll
    for (int nf = 0; nf < NF; ++nf) {
      const int oc = ocn[nf];
      float* op = dst + (PS ? (size_t)cs * osz : 0)
                + ((size_t)(b * Cout + oc) * OH + h) * OW + ow0 + l4 * 4;
      f4 r = acc[mf][nf];
      if (!PS) {
        const float bo = bias[oc];
#pragma unroll
        for (int j = 0; j < 4; ++j) r[j] = fmaxf(r[j] + bo, 0.f);
      }
      *(f4*)op = r;
    }
  }
}

// ===========================================================================
// VALU conv (R4 path) — used for 1_1 and the wmode=0 fallback.
// ===========================================================================
template<int S, int HK, int PS, int KC, int TW, int OCB>
__global__ __launch_bounds__(256, 2) void conv3x3_k(
    const float* __restrict__ src, const float* __restrict__ wsrc, int wmode,
    const float* __restrict__ bias, const float* __restrict__ kern,
    float* __restrict__ dst, int Cin, int Cout, int H, int CS)
{
  constexpr int TH  = 256 / TW;
  constexpr int RH  = TH * S + 2;
  constexpr int RW  = TW * S + 2;
  constexpr int RW4 = (RW + 3) & ~3;
  constexpr int RWs = (RW4 % 8 == 0) ? RW4 + 4 : RW4;
  constexpr int CPT = TW / 8;
  constexpr int OPT = OCB / 8;
  constexpr int TOTX = KC * RH * RW;
  constexpr int NLX  = (TOTX + 255) / 256;
  constexpr int TOTW = KC * 9 * OCB;
  constexpr int NLW  = (TOTW + 255) / 256;

  __shared__ __align__(16) float xs[KC][RH][RWs];
  __shared__ __align__(16) float wsm[KC][9][OCB];

  const int W = H, HW = H * W;
  const int OH = H / S, OW = W / S;
  const int tid  = threadIdx.x;
  const int ocg  = tid >> 5;
  const int pxg  = tid & 31;
  const int prow = pxg / CPT;
  const int pcol = (pxg % CPT) * 8;
  const int tiles_w = OW / TW;
  const int th0 = (blockIdx.x / tiles_w) * TH;
  const int tw0 = (blockIdx.x % tiles_w) * TW;
  const int ocb = blockIdx.y * OCB;
  const int bz  = blockIdx.z;
  const int b   = bz / CS, cs = bz - b * CS;
  const int CinS   = Cin / CS;
  const int c_base = cs * CinS;
  const int c_end  = c_base + CinS;
  const int oh  = th0 + prow;
  const int ow0 = tw0 + pcol;
  const int oc0 = ocb + ocg * OPT;

  float acc[OPT][8];
#pragma unroll
  for (int o = 0; o < OPT; ++o)
#pragma unroll
    for (int p = 0; p < 8; ++p) acc[o][p] = 0.f;

  float kf[HK ? 9 : 1][8];
  if (HK) {
#pragma unroll
    for (int t = 0; t < 9; ++t) {
      const float* kp = kern + ((size_t)(b * 9 + t) * H + (size_t)oh * S) * W
                             + (size_t)ow0 * S;
      if constexpr (S == 1) {
        f4 a = *(const f4*)kp; f4 c = *(const f4*)(kp + 4);
#pragma unroll
        for (int p = 0; p < 4; ++p) { kf[t][p] = a[p]; kf[t][4 + p] = c[p]; }
      } else {
#pragma unroll
        for (int p = 0; p < 8; ++p) kf[t][p] = kp[2 * p];
      }
    }
  }

  const float* xb = src + (size_t)b * Cin * HW;

  float xr[NLX], wr[NLW];

  auto loadX = [&](int c0) {
#pragma unroll
    for (int l = 0; l < NLX; ++l) {
      const int idx = tid + l * 256;
      float v = 0.f;
      if (idx < TOTX) {
        int kc  = idx / (RH * RW);
        int rem = idx - kc * (RH * RW);
        int r   = rem / RW;
        int col = rem - r * RW;
        int ih = th0 * S + r - 1;
        int iw = tw0 * S + col - 1;
        if (ih >= 0 && ih < H && iw >= 0 && iw < W)
          v = xb[(size_t)(c0 + kc) * HW + (size_t)ih * W + iw];
      }
      xr[l] = v;
    }
  };
  auto storeX = [&]() {
#pragma unroll
    for (int l = 0; l < NLX; ++l) {
      const int idx = tid + l * 256;
      if (idx < TOTX) {
        int kc  = idx / (RH * RW);
        int rem = idx - kc * (RH * RW);
        int r   = rem / RW;
        int col = rem - r * RW;
        xs[kc][r][col] = xr[l];
      }
    }
  };
  auto loadW = [&](int c0) {
#pragma unroll
    for (int l = 0; l < NLW; ++l) {
      const int idx = tid + l * 256;
      if (idx < TOTW) {
        int kc  = idx / (9 * OCB);
        int rem = idx - kc * (9 * OCB);
        int t   = rem / OCB;
        int o   = rem - t * OCB;
        wr[l] = wmode
          ? wsrc[((size_t)(c0 + kc) * 9 + t) * Cout + ocb + o]
          : wsrc[((size_t)(ocb + o) * Cin + (c0 + kc)) * 9 + t];
      }
    }
  };
  auto storeW = [&]() {
#pragma unroll
    for (int l = 0; l < NLW; ++l) {
      const int idx = tid + l * 256;
      if (idx < TOTW) {
        int kc  = idx / (9 * OCB);
        int rem = idx - kc * (9 * OCB);
        int t   = rem / OCB;
        int o   = rem - t * OCB;
        wsm[kc][t][o] = wr[l];
      }
    }
  };

  loadX(c_base);
  loadW(c_base);

  for (int c0 = c_base; c0 < c_end; c0 += KC) {
    storeX();
    storeW();
    __syncthreads();
    if (c0 + KC < c_end) { loadX(c0 + KC); loadW(c0 + KC); }

#pragma unroll 1
    for (int kc = 0; kc < KC; ++kc) {
#pragma unroll
      for (int di = 0; di < 3; ++di) {
        const float* xrow = &xs[kc][prow * S + di][pcol * S];
        f4 xa, xbv, xc, xd; f2 xe2; float xe;
        xa  = *(const f4*)xrow;
        xbv = *(const f4*)(xrow + 4);
        if constexpr (S == 1) {
          xe2 = *(const f2*)(xrow + 8);
        } else {
          xc = *(const f4*)(xrow + 8);
          xd = *(const f4*)(xrow + 12);
          xe = xrow[16];
        }
        auto xget = [&](int q) -> float {
          if constexpr (S == 1)
            return (q < 4) ? xa[q] : (q < 8) ? xbv[q - 4] : xe2[q - 8];
          else
            return (q < 4) ? xa[q] : (q < 8) ? xbv[q - 4]
                 : (q < 12) ? xc[q - 8] : (q < 16) ? xd[q - 12] : xe;
        };

#pragma unroll
        for (int dj = 0; dj < 3; ++dj) {
          const int t = di * 3 + dj;
          f4 wv[OPT / 4 > 0 ? OPT / 4 : 1];
#pragma unroll
          for (int u = 0; u < OPT / 4; ++u)
            wv[u] = *(const f4*)&wsm[kc][t][ocg * OPT + 4 * u];

          float xq[8];
#pragma unroll
          for (int p = 0; p < 8; ++p) {
            float xvv = xget(S * p + dj);
            xq[p] = HK ? xvv * kf[t][p] : xvv;
          }
#pragma unroll
          for (int o = 0; o < OPT; ++o) {
            const float w = wv[o >> 2][o & 3];
#pragma unroll
            for (int p = 0; p < 8; ++p)
              acc[o][p] = fmaf(w, xq[p], acc[o][p]);
          }
        }
      }
    }
    __syncthreads();
  }

  const size_t osz = (size_t)2 * Cout * OH * OW;
#pragma unroll
  for (int o = 0; o < OPT; ++o) {
    const int oc = oc0 + o;
    float* orow = dst + (PS ? (size_t)cs * osz : 0)
                + ((size_t)b * Cout + oc) * OH * OW + (size_t)oh * OW + ow0;
    f4 r0, r1;
    if constexpr (PS) {
#pragma unroll
      for (int p = 0; p < 4; ++p) { r0[p] = acc[o][p]; r1[p] = acc[o][4 + p]; }
    } else {
      const float bo = bias[oc];
#pragma unroll
      for (int p = 0; p < 4; ++p) {
        r0[p] = fmaxf(acc[o][p] + bo, 0.f);
        r1[p] = fmaxf(acc[o][4 + p] + bo, 0.f);
      }
    }
    *(f4*)orow = r0; *(f4*)(orow + 4) = r1;
  }
}

// ---------------------------------------------------------------------------
// PAC stage 1 (partial sums per channel-slice)
// ---------------------------------------------------------------------------
template<int KCC>
__global__ __launch_bounds__(256) void pac_s1(
    const float* __restrict__ g, float* __restrict__ s,
    int C, int H, int W, int CS)
{
  __shared__ float xs[KCC][18][19];
  const int tid = threadIdx.x;
  const int pr = tid >> 4, pc = tid & 15;
  const int tiles_w = W / 16;
  const int tile = blockIdx.x;
  const int th0 = (tile / tiles_w) * 16, tw0 = (tile % tiles_w) * 16;
  const int bz = blockIdx.y;
  const int b = bz / CS, cs = bz - b * CS;
  const int CinS = C / CS, c0b = cs * CinS;

  float acc[9];
#pragma unroll
  for (int t = 0; t < 9; ++t) acc[t] = 0.f;

  const float* gb = g + (size_t)b * C * H * W;
  for (int c0 = c0b; c0 < c0b + CinS; c0 += KCC) {
    for (int idx = tid; idx < KCC * 18 * 18; idx += 256) {
      int kc = idx / 324;
      int rem = idx - kc * 324;
      int r = rem / 18, col = rem - r * 18;
      int ih = th0 + r - 1, iw = tw0 + col - 1;
      float v = 0.f;
      if (ih >= 0 && ih < H && iw >= 0 && iw < W)
        v = gb[(size_t)(c0 + kc) * H * W + (size_t)ih * W + iw];
      xs[kc][r][col] = v;
    }
    __syncthreads();
#pragma unroll
    for (int kc = 0; kc < KCC; ++kc) {
      float xcv = xs[kc][pr + 1][pc + 1];
#pragma unroll
      for (int di = 0; di < 3; ++di)
#pragma unroll
        for (int dj = 0; dj < 3; ++dj) {
          float d = xs[kc][pr + di][pc + dj] - xcv;
          acc[di * 3 + dj] = fmaf(d, d, acc[di * 3 + dj]);
        }
    }
    __syncthreads();
  }

  const size_t HWs = (size_t)H * W;
  float* sp = s + ((size_t)(cs * 2 + b) * 9) * HWs
            + (size_t)(th0 + pr) * W + tw0 + pc;
#pragma unroll
  for (int t = 0; t < 9; ++t) sp[t * HWs] = acc[t];
}

__global__ __launch_bounds__(256) void pac_sum_exp(
    const float* __restrict__ P, float* __restrict__ k, float c2, int n, int CS)
{
  int i = blockIdx.x * 256 + threadIdx.x;
  if (i < n) {
    float s = 0.f;
    for (int cs = 0; cs < CS; ++cs) s += P[(size_t)cs * n + i];
    k[i] = expf(-0.5f * c2 * s);
  }
}

__global__ __launch_bounds__(256) void sum_relu_k(
    const float* __restrict__ P, const float* __restrict__ bias,
    float* __restrict__ out, int C, int HW, int n, int CS)
{
  int i = blockIdx.x * 256 + threadIdx.x;
  if (i < n) {
    float s = 0.f;
    for (int cs = 0; cs < CS; ++cs) s += P[(size_t)cs * n + i];
    int c = (i / HW) % C;
    out[i] = fmaxf(s + bias[c], 0.f);
  }
}

// ---------------------------------------------------------------------------
// weight prep: hi/lo bf16 split for 13 MFMA layers (all but layer 0)
// ---------------------------------------------------------------------------
struct SPack13 {
  const float* src[13];
  int ci[13];
  int co[13];
  size_t off[13];
};

__global__ __launch_bounds__(256) void split_w13(SPack13 p, ushort_t* hi, ushort_t* lo)
{
  for (int l = 0; l < 13; ++l) {
    const int ci = p.ci[l], co = p.co[l];
    const int n = 9 * ci * co;
    const float* s = p.src[l];
    ushort_t* ph = hi + p.off[l];
    ushort_t* pl = lo + p.off[l];
    for (int idx = blockIdx.x * 256 + threadIdx.x; idx < n;
         idx += gridDim.x * 256) {
      int c = idx % ci;
      int r = idx / ci;
      int oc = r % co;
      int t = r / co;
      float w = s[((size_t)oc * ci + c) * 9 + t];
      uint_t u = __float_as_uint(w);
      uint_t hb = u & 0xffff0000u;
      float lov = w - __uint_as_float(hb);
      ph[idx] = (ushort_t)(hb >> 16);
      pl[idx] = (ushort_t)(__float_as_uint(lov) >> 16);
    }
  }
}

// ---------------------------------------------------------------------------
extern "C" void kernel_launch(void* const* d_in, const int* in_sizes, int n_in,
                              void* d_out, int out_size, void* d_ws, size_t ws_size,
                              hipStream_t stream)
{
  (void)in_sizes; (void)n_in; (void)out_size;
  const float* x = (const float*)d_in[0];
  const float* Wp[14];
  const float* Bp[14];
  for (int l = 0; l < 14; ++l) {
    Wp[l] = (const float*)d_in[1 + 2 * l];
    Bp[l] = (const float*)d_in[2 + 2 * l];
  }
  float* out = (float*)d_out;
  float* ws  = (float*)d_ws;

  float*    A   = ws + OFF_A;
  float*    Bf  = ws + OFF_B;
  float*    P   = ws + OFF_P;
  ushort_t* WHI = (ushort_t*)(ws + OFF_WH);
  ushort_t* WLO = (ushort_t*)(ws + OFF_WL);

  const int ci[14] = {1,64,64, 64,128,128, 128,256,256, 256,512,512, 512,1024};
  const int co[14] = {64,64,64, 128,128,128, 256,256,256, 512,512,512, 1024,1024};

  const int wmode = (ws_size >= (size_t)WS_FULL_FLOATS * 4) ? 1 : 0;

  float* h1 = out + O_H1;
  float* h2 = out + O_H2;
  float* h3 = out + O_H3;
  float* h4 = out + O_H4;
  float* h5 = out + O_H5;
  float* k2 = out + O_K2;
  float* k3 = out + O_K3;
  float* k4 = out + O_K4;
  float* k5 = out + O_K5;

  auto epi = [&](const float* p, const float* bias, float* dst, int C, int HWo, int CS) {
    int n = 2 * C * HWo;
    sum_relu_k<<<(n + 255) / 256, 256, 0, stream>>>(p, bias, dst, C, HWo, n, CS);
  };
  auto pac = [&](const float* g, float* kdst, int C, int H, int CS, float c2) {
    dim3 g1((H / 16) * (H / 16), 2 * CS);
    pac_s1<4><<<g1, 256, 0, stream>>>(g, P, C, H, H, CS);
    int n = 2 * 9 * H * H;
    pac_sum_exp<<<(n + 255) / 256, 256, 0, stream>>>(P, kdst, c2, n, CS);
  };

  if (wmode) {
    // ---- prep: hi/lo bf16 split, layers 1..13 ----
    SPack13 sp;
    size_t moff[13];
    {
      size_t off = 0;
      for (int i = 0; i < 13; ++i) {
        int l = i + 1;
        sp.src[i] = Wp[l];
        sp.ci[i] = ci[l];
        sp.co[i] = co[l];
        sp.off[i] = off;
        moff[i] = off;
        off += (size_t)ci[l] * co[l] * 9;
      }
    }
    split_w13<<<2048, 256, 0, stream>>>(sp, WHI, WLO);

#define CONV_M(HKv, PSv, NFv, src_, li, kern_, dst_, Cin_, Cout_, H_, CS_)        \
    do {                                                                          \
      dim3 g_(((H_) / 4) * ((H_) / 16), (Cout_) / (32 * (NFv)), 2 * (CS_));       \
      conv_mfma_k<HKv, PSv, NFv><<<g_, 256, 0, stream>>>(                         \
          src_, WHI + moff[(li) - 1], WLO + moff[(li) - 1], Bp[li], kern_, dst_,  \
          Cin_, Cout_, H_, CS_);                                                  \
    } while (0)

#define CONV_M2(HKv, PSv, NFv, src_, li, kern_, dst_, Cin_, Cout_, H_, CS_)       \
    do {                                                                          \
      const int OH_ = (H_) / 2;                                                   \
      dim3 g_((OH_ / 4) * (OH_ / 16), (Cout_) / (32 * (NFv)), 2 * (CS_));         \
      conv_mfma_s2_k<HKv, PSv, NFv><<<g_, 256, 0, stream>>>(                      \
          src_, WHI + moff[(li) - 1], WLO + moff[(li) - 1], Bp[li], kern_, dst_,  \
          Cin_, Cout_, H_, CS_);                                                  \
    } while (0)

    // ---- 1_1: VALU, raw weights (Cin=1) ----
    {
      dim3 g_((256 / 8) * (256 / 32), 64 / 64, 2);
      conv3x3_k<1,0,0,1,32,64><<<g_, 256, 0, stream>>>(
          x, Wp[0], 0, Bp[0], nullptr, A, 1, 64, 256, 1);
    }
    CONV_M (0,0,2, A, 1, nullptr, h1, 64, 64, 256, 1);                 // 1_2
    CONV_M2(0,0,2, h1, 2, nullptr, Bf, 64, 64, 256, 1);                // 1_3 -> Bf

    pac(Bf, k2, 64, 128, 8, 1e-8f);

    CONV_M (1,0,4, Bf, 3, k2, A,  64, 128, 128, 1);                    // 2_1
    CONV_M (1,0,4, A,  4, k2, h2, 128, 128, 128, 1);                   // 2_2
    CONV_M2(1,1,4, h2, 5, k2, P, 128, 128, 128, 2);                    // 2_3
    epi(P, Bp[5], Bf, 128, 64 * 64, 2);

    pac(Bf, k3, 128, 64, 16, 1e-8f);

    CONV_M (1,0,4, Bf, 6, k3, A,  128, 256, 64, 1);                    // 3_1
    CONV_M (1,0,4, A,  7, k3, h3, 256, 256, 64, 1);                    // 3_2
    CONV_M2(1,1,4, h3, 8, k3, P, 256, 256, 64, 4);                     // 3_3
    epi(P, Bp[8], Bf, 256, 32 * 32, 4);

    pac(Bf, k4, 256, 32, 64, 4.0f);

    CONV_M (1,1,4, Bf, 9, k4, P, 256, 512, 32, 2);                     // 4_1
    epi(P, Bp[9], A, 512, 32 * 32, 2);
    CONV_M (1,1,4, A,  10, k4, P, 512, 512, 32, 2);                    // 4_2
    epi(P, Bp[10], h4, 512, 32 * 32, 2);
    CONV_M2(1,1,4, h4, 11, k4, P, 512, 512, 32, 8);                    // 4_3
    epi(P, Bp[11], Bf, 512, 16 * 16, 8);

    pac(Bf, k5, 512, 16, 128, 1e-8f);

    CONV_M (1,1,4, Bf, 12, k5, P, 512, 1024, 16, 4);                   // 5_1
    epi(P, Bp[12], A, 1024, 16 * 16, 4);
    CONV_M (1,1,4, A,  13, k5, P, 1024, 1024, 16, 4);                  // 5_2
    epi(P, Bp[13], h5, 1024, 16 * 16, 4);

#undef CONV_M
#undef CONV_M2
  } else {
    // ---- fallback: full VALU path with raw weights (R4 structure) ----
#define CONV_R(Sv, HKv, PSv, KCv, TWv, OCBv, src_, wi, kern_, dst_, Cin_, Cout_, H_, CS_) \
    do {                                                                          \
      const int OH_ = (H_) / (Sv), TH_ = 256 / (TWv);                             \
      dim3 g_((OH_ / TH_) * (OH_ / (TWv)), (Cout_) / (OCBv), 2 * (CS_));          \
      conv3x3_k<Sv, HKv, PSv, KCv, TWv, OCBv><<<g_, 256, 0, stream>>>(            \
          src_, Wp[wi], 0, Bp[wi], kern_, dst_, Cin_, Cout_, H_, CS_);            \
    } while (0)

    CONV_R(1,0,0,1,32,64, x,  0, nullptr, A,  1,  64, 256, 1);
    CONV_R(1,0,0,8,32,64, A,  1, nullptr, h1, 64, 64, 256, 1);
    CONV_R(2,0,1,4,32,32, h1, 2, nullptr, P, 64, 64, 256, 2);
    epi(P, Bp[2], Bf, 64, 128 * 128, 2);
    pac(Bf, k2, 64, 128, 8, 1e-8f);
    CONV_R(1,1,0,8,32,32, Bf, 3, k2, A,  64, 128, 128, 1);
    CONV_R(1,1,0,8,32,32, A,  4, k2, h2, 128, 128, 128, 1);
    CONV_R(2,1,1,4,32,32, h2, 5, k2, P, 128, 128, 128, 4);
    epi(P, Bp[5], Bf, 128, 64 * 64, 4);
    pac(Bf, k3, 128, 64, 16, 1e-8f);
    CONV_R(1,1,1,8,32,32, Bf, 6, k3, P, 128, 256, 64, 2);
    epi(P, Bp[6], A, 256, 64 * 64, 2);
    CONV_R(1,1,1,8,32,32, A,  7, k3, P, 256, 256, 64, 2);
    epi(P, Bp[7], h3, 256, 64 * 64, 2);
    CONV_R(2,1,1,4,32,32, h3, 8, k3, P, 256, 256, 64, 8);
    epi(P, Bp[8], Bf, 256, 32 * 32, 8);
    pac(Bf, k4, 256, 32, 64, 4.0f);
    CONV_R(1,1,1,8,32,32, Bf, 9,  k4, P, 256, 512, 32, 4);
    epi(P, Bp[9], A, 512, 32 * 32, 4);
    CONV_R(1,1,1,8,32,32, A,  10, k4, P, 512, 512, 32, 4);
    epi(P, Bp[10], h4, 512, 32 * 32, 4);
    CONV_R(2,1,1,4,16,32, h4, 11, k4, P, 512, 512, 32, 16);
    epi(P, Bp[11], Bf, 512, 16 * 16, 16);
    pac(Bf, k5, 512, 16, 128, 1e-8f);
    CONV_R(1,1,1,8,16,32, Bf, 12, k5, P, 512, 1024, 16, 8);
    epi(P, Bp[12], A, 1024, 16 * 16, 8);
    CONV_R(1,1,1,8,16,32, A,  13, k5, P, 1024, 1024, 16, 8);
    epi(P, Bp[13], h5, 1024, 16 * 16, 8);
#undef CONV_R
  }
}